// Round 3
// baseline (422.007 us; speedup 1.0000x reference)
//
#include <hip/hip_runtime.h>

typedef unsigned short ushort_t;
typedef unsigned int uint_t;

typedef __bf16 bf16x8 __attribute__((ext_vector_type(8)));
typedef float f32x4 __attribute__((ext_vector_type(4)));

union BFU { ushort_t u; __bf16 h; };

__device__ __forceinline__ float bf2f(uint_t u) {
    union { uint_t i; float f; } v; v.i = u << 16; return v.f;
}
__device__ __forceinline__ ushort_t f2bf(float f) {
    union { float f; uint_t i; } v; v.f = f;
    uint_t r = v.i + 0x7fffu + ((v.i >> 16) & 1u);
    return (ushort_t)(r >> 16);
}
// mode: 1 = bf16 storage, 0 = fp32 storage
__device__ __forceinline__ float loadF(const void* p, size_t i, int isBf16) {
    return isBf16 ? bf2f((uint_t)((const ushort_t*)p)[i]) : ((const float*)p)[i];
}

// flags[0..10]: x,W1,b1,W2,b2,W3,b3,Wres,bres,Wlin,blin  (1=bf16, 0=fp32)
// flags[11]: edge_index is int64 (1) or int32 (0)
struct DetectArgs {
    const void* t[11];
    int elems[11];
    const int* ei;
    int* flags;
};

__device__ __forceinline__ int detect_one(const void* p, int elems) {
    const uint_t* w = (const uint_t*)p;
    int n = elems / 2; if (n > 64) n = 64;
    int cnt = 0;
    for (int k = 0; k < n; ++k) {
        uint_t f = (w[k] >> 7) & 0xFFu;
        cnt += (f >= 100u && f <= 135u);
    }
    return (cnt * 10 >= n * 6) ? 1 : 0;
}

// ---------------- weight pack + dtype detection + deg zeroing ----------------
__global__ void k_pack(DetectArgs a,
                       ushort_t* __restrict__ Tcat, ushort_t* __restrict__ T2,
                       ushort_t* __restrict__ T3, ushort_t* __restrict__ Tl,
                       int* __restrict__ deg, int N, uint_t* __restrict__ Hz) {
    __shared__ int lflag;
    int i = blockIdx.x * blockDim.x + threadIdx.x;
    if (i < N) deg[i] = 0;                         // fused memset
    // zero the sentinel row H'[N] (padding lanes in k_agg gather it)
    if (blockIdx.x == 1 && threadIdx.x < 64) Hz[threadIdx.x] = 0u;
    const int SQ = 128 * 128;
    int m = (i < 4 * SQ) ? (i / SQ) : 4;           // uniform per block (SQ%256==0)
    int fid = (m == 0) ? 1 : (m == 1) ? 3 : (m == 2) ? 5 : (m == 3) ? 7 : 9;
    const void* W = a.t[fid];

    if (threadIdx.x == 0) lflag = detect_one(W, a.elems[fid]);
    if (blockIdx.x == 0 && threadIdx.x >= 64 && threadIdx.x < 75) {
        int t = threadIdx.x - 64;
        a.flags[t] = detect_one(a.t[t], a.elems[t]);
    }
    if (blockIdx.x == 0 && threadIdx.x == 75) {
        int nz = 0;
        for (int k = 0; k < 64; ++k) nz += (a.ei[2 * k + 1] != 0);
        a.flags[11] = (nz == 0) ? 1 : 0;
    }
    __syncthreads();
    int isb = lflag;

    if (i < 4 * SQ) {
        int r = i % SQ;
        int k = r / 128, f = r % 128;
        ushort_t* T = (m == 0) ? Tcat : (m == 1) ? T2 : (m == 2) ? T3 : (Tcat + SQ);
        T[f * 128 + k] = f2bf(loadF(W, (size_t)k * 128 + f, isb));
    } else if (i < 4 * SQ + 128 * 64) {
        int r = i - 4 * SQ;
        int k = r / 64, f = r % 64;
        Tl[f * 128 + k] = f2bf(loadF(W, (size_t)k * 64 + f, isb));
    }
}

// ---------------- degree + rank: the ONLY atomic pass ----------------
__global__ void k_deg(const int* __restrict__ ei, int E, int N,
                      const int* __restrict__ flags, int* __restrict__ deg,
                      int2* __restrict__ tmp) {
    int i = blockIdx.x * blockDim.x + threadIdx.x;
    int e0 = i * 4;
    if (e0 >= E) return;
    int is64 = flags[11];
    if (e0 + 3 < E && (E & 3) == 0) {
        int d[4];
        if (is64) {
            int4 va = *(const int4*)(ei + 2 * E + 2 * e0);
            int4 vb = *(const int4*)(ei + 2 * E + 2 * e0 + 4);
            d[0] = va.x; d[1] = va.z; d[2] = vb.x; d[3] = vb.z;
        } else {
            int4 va = *(const int4*)(ei + E + e0);
            d[0] = va.x; d[1] = va.y; d[2] = va.z; d[3] = va.w;
        }
        int l[4]; bool ok[4];
#pragma unroll
        for (int k = 0; k < 4; ++k) ok[k] = (unsigned)d[k] < (unsigned)N;
#pragma unroll
        for (int k = 0; k < 4; ++k)
            l[k] = ok[k] ? atomicAdd(&deg[d[k]], 1) : 0;
        int4 t01, t23;
        t01.x = ok[0] ? d[0] : -1; t01.y = l[0];
        t01.z = ok[1] ? d[1] : -1; t01.w = l[1];
        t23.x = ok[2] ? d[2] : -1; t23.y = l[2];
        t23.z = ok[3] ? d[3] : -1; t23.w = l[3];
        *(int4*)(tmp + e0) = t01;
        *(int4*)(tmp + e0 + 2) = t23;
    } else {
        for (int e = e0; e < E && e < e0 + 4; ++e) {
            int dd = is64 ? ei[2 * E + 2 * e] : ei[E + e];
            bool ok = (unsigned)dd < (unsigned)N;
            int l = ok ? atomicAdd(&deg[dd], 1) : 0;
            tmp[e] = make_int2(ok ? dd : -1, l);
        }
    }
}

// ---- scan: k_bsum (per-1024-chunk sums) + k_rowptr (self-computed offset) ----

__global__ __launch_bounds__(256) void k_bsum(const int* __restrict__ deg, int n,
                                              int* __restrict__ bsum) {
    int base = blockIdx.x * 1024;
    int local = 0;
#pragma unroll
    for (int j = 0; j < 4; ++j) {
        int idx = base + threadIdx.x + j * 256;
        if (idx < n) local += deg[idx];
    }
    __shared__ int s[4];
#pragma unroll
    for (int off = 32; off; off >>= 1) local += __shfl_down(local, off, 64);
    if ((threadIdx.x & 63) == 0) s[threadIdx.x >> 6] = local;
    __syncthreads();
    if (threadIdx.x == 0) bsum[blockIdx.x] = s[0] + s[1] + s[2] + s[3];
}

// computes own block offset by reducing bsum[0..b-1] (nb <= 64, single wave)
__global__ __launch_bounds__(256) void k_rowptr(const int* __restrict__ deg,
                                                const int* __restrict__ bsum, int n,
                                                int* __restrict__ row_ptr,
                                                float* __restrict__ dinv) {
    __shared__ int s[256];
    __shared__ int sboff;
    int t = threadIdx.x;

    if (t < 64) {
        int v = (t < blockIdx.x) ? bsum[t] : 0;   // exclusive: blocks before me
#pragma unroll
        for (int off = 32; off; off >>= 1) v += __shfl_down(v, off, 64);
        if (t == 0) sboff = v;
    }

    int base = blockIdx.x * 1024 + t * 4;
    int v0 = (base + 0 < n) ? deg[base + 0] : 0;
    int v1 = (base + 1 < n) ? deg[base + 1] : 0;
    int v2 = (base + 2 < n) ? deg[base + 2] : 0;
    int v3 = (base + 3 < n) ? deg[base + 3] : 0;
    int tot = v0 + v1 + v2 + v3;
    s[t] = tot;
    __syncthreads();
    for (int off = 1; off < 256; off <<= 1) {
        int u = (t >= off) ? s[t - off] : 0;
        __syncthreads();
        s[t] += u;
        __syncthreads();
    }
    int run = sboff + ((t == 0) ? 0 : s[t - 1]);
    int vals[4] = {v0, v1, v2, v3};
#pragma unroll
    for (int j = 0; j < 4; ++j) {
        int idx = base + j;
        if (idx < n) {
            row_ptr[idx] = run;
            run += vals[j];
            float df = (float)vals[j] + 1.0f;
            dinv[idx] = rsqrtf(df);
        }
    }
    if (blockIdx.x == gridDim.x - 1 && t == 255) row_ptr[n] = sboff + s[255];
}

// ------- scatter CSR (NO atomics): pos = row_ptr[d] + rank; col only (4B/edge) -------
__global__ void k_scatter(const int* __restrict__ ei, int E, int N,
                          const int* __restrict__ flags,
                          const int* __restrict__ row_ptr,
                          const int2* __restrict__ tmp,
                          uint_t* __restrict__ colw) {
    int i = blockIdx.x * blockDim.x + threadIdx.x;
    int e0 = i * 4;
    if (e0 >= E) return;
    int is64 = flags[11];
    if (e0 + 3 < E && (E & 3) == 0) {
        int s[4];
        if (is64) {
            int4 sa = *(const int4*)(ei + 2 * e0);
            int4 sb = *(const int4*)(ei + 2 * e0 + 4);
            s[0] = sa.x; s[1] = sa.z; s[2] = sb.x; s[3] = sb.z;
        } else {
            int4 sa = *(const int4*)(ei + e0);
            s[0] = sa.x; s[1] = sa.y; s[2] = sa.z; s[3] = sa.w;
        }
        int4 t01 = *(const int4*)(tmp + e0);
        int4 t23 = *(const int4*)(tmp + e0 + 2);
        int d[4] = {t01.x, t01.z, t23.x, t23.z};
        int l[4] = {t01.y, t01.w, t23.y, t23.w};
        int ss[4];
#pragma unroll
        for (int k = 0; k < 4; ++k)
            ss[k] = ((unsigned)s[k] < (unsigned)N) ? s[k] : 0;
#pragma unroll
        for (int k = 0; k < 4; ++k) {
            if (d[k] >= 0)
                colw[row_ptr[d[k]] + l[k]] = (uint_t)ss[k];
        }
    } else {
        for (int e = e0; e < E && e < e0 + 4; ++e) {
            int sv = is64 ? ei[2 * e] : ei[e];
            int2 tv = tmp[e];
            if (tv.x >= 0) {
                int ssv = ((unsigned)sv < (unsigned)N) ? sv : 0;
                colw[row_ptr[tv.x] + tv.y] = (uint_t)ssv;
            }
        }
    }
}

// ===== LDS-staged GEMM, 64 rows/block =====

template <int NCT>
__device__ __forceinline__ void stage_B(const ushort_t* __restrict__ WT, uint4* lds) {
    int t = threadIdx.x;
#pragma unroll
    for (int i = 0; i < NCT; ++i) {
        int g = i * 256 + t;
        uint4 v = ((const uint4*)WT)[g];
        int col = g >> 4, k8 = g & 15;
        int c = col >> 4, l16c = col & 15;
        int kk = k8 >> 2, q = k8 & 3;
        lds[((kk * NCT + c) << 6) + (q << 4) + l16c] = v;
    }
    __syncthreads();
}

__device__ __forceinline__ void load_A1(const void* __restrict__ A, int a16,
                                        int ar, int quad, bf16x8 af[4]) {
    if (a16) {
        const ushort_t* p = (const ushort_t*)A + (size_t)ar * 128 + quad * 8;
#pragma unroll
        for (int kk = 0; kk < 4; ++kk) af[kk] = *(const bf16x8*)(p + kk * 32);
    } else {
        const float* p = (const float*)A + (size_t)ar * 128 + quad * 8;
#pragma unroll
        for (int kk = 0; kk < 4; ++kk) {
            f32x4 u0 = *(const f32x4*)(p + kk * 32);
            f32x4 u1 = *(const f32x4*)(p + kk * 32 + 4);
#pragma unroll
            for (int j = 0; j < 4; ++j) {
                BFU e;
                e.u = f2bf(u0[j]); af[kk][j] = e.h;
                e.u = f2bf(u1[j]); af[kk][j + 4] = e.h;
            }
        }
    }
}

// rowscale != nullptr: store C[row] = acc*rowscale[row] (+bias)  -- folds D^-1/2
template <int NCT>
__global__ __launch_bounds__(256, 4) void k_gemm2(const void* __restrict__ A, int aFid, int aFix,
                                                  const ushort_t* __restrict__ WT,
                                                  const void* __restrict__ bias, int bFid,
                                                  void* __restrict__ C, int cFix,
                                                  int M, const int* __restrict__ flags,
                                                  const float* __restrict__ rowscale) {
    __shared__ uint4 lds[NCT * 256];
    stage_B<NCT>(WT, lds);

    const int F = NCT * 16;
    int t = threadIdx.x;
    int wave = t >> 6, lane = t & 63;
    int quad = lane >> 4, l16 = lane & 15;
    int row0 = blockIdx.x * 64 + wave * 16;

    int a16 = (aFid >= 0) ? flags[aFid] : aFix;
    int ar = row0 + l16; if (ar >= M) ar = M - 1;

    bf16x8 af[4];
    load_A1(A, a16, ar, quad, af);

    f32x4 acc[NCT];
#pragma unroll
    for (int c = 0; c < NCT; ++c) acc[c] = (f32x4){0.f, 0.f, 0.f, 0.f};

#pragma unroll
    for (int kk = 0; kk < 4; ++kk) {
#pragma unroll
        for (int c = 0; c < NCT; ++c) {
            bf16x8 b = *(const bf16x8*)&lds[((kk * NCT + c) << 6) + lane];
            acc[c] = __builtin_amdgcn_mfma_f32_16x16x32_bf16(af[kk], b, acc[c], 0, 0, 0);
        }
    }

    float rs[4];
#pragma unroll
    for (int q = 0; q < 4; ++q) {
        int row = row0 + quad * 4 + q;
        rs[q] = (rowscale && row < M) ? rowscale[row] : 1.0f;
    }

    int bf = (bias && bFid >= 0) ? flags[bFid] : 1;
#pragma unroll
    for (int c = 0; c < NCT; ++c) {
        int colg = c * 16 + l16;
        float bv = bias ? loadF(bias, colg, bf) : 0.0f;
#pragma unroll
        for (int q = 0; q < 4; ++q) {
            int row = row0 + quad * 4 + q;
            if (row < M) {
                float v = acc[c][q] * rs[q] + bv;
                if (cFix) ((ushort_t*)C)[(size_t)row * F + colg] = f2bf(v);
                else      ((float*)C)[(size_t)row * F + colg] = v;
            }
        }
    }
}

// layer-1 dual output, two-phase staging (32 KB LDS); Hout scaled by dinv, Xres not
__global__ __launch_bounds__(256, 4) void k_gemm_l1(const void* __restrict__ A,
                                                    const ushort_t* __restrict__ Tcat,
                                                    const void* __restrict__ bres,
                                                    ushort_t* __restrict__ Hout,
                                                    ushort_t* __restrict__ Xres,
                                                    int M, const int* __restrict__ flags,
                                                    const float* __restrict__ dinv) {
    __shared__ uint4 lds[8 * 256];
    int t = threadIdx.x;
    int wave = t >> 6, lane = t & 63;
    int quad = lane >> 4, l16 = lane & 15;
    int row0 = blockIdx.x * 64 + wave * 16;

    int a16 = flags[0];
    int ar = row0 + l16; if (ar >= M) ar = M - 1;

    bf16x8 af[4];
    load_A1(A, a16, ar, quad, af);

    float rs[4];
#pragma unroll
    for (int q = 0; q < 4; ++q) {
        int row = row0 + quad * 4 + q;
        rs[q] = (row < M) ? dinv[row] : 1.0f;
    }

    stage_B<8>(Tcat, lds);
    {
        f32x4 acc[8];
#pragma unroll
        for (int c = 0; c < 8; ++c) acc[c] = (f32x4){0.f, 0.f, 0.f, 0.f};
#pragma unroll
        for (int kk = 0; kk < 4; ++kk) {
#pragma unroll
            for (int c = 0; c < 8; ++c) {
                bf16x8 b = *(const bf16x8*)&lds[((kk * 8 + c) << 6) + lane];
                acc[c] = __builtin_amdgcn_mfma_f32_16x16x32_bf16(af[kk], b, acc[c], 0, 0, 0);
            }
        }
#pragma unroll
        for (int c = 0; c < 8; ++c) {
            int colg = c * 16 + l16;
#pragma unroll
            for (int q = 0; q < 4; ++q) {
                int row = row0 + quad * 4 + q;
                if (row < M) Hout[(size_t)row * 128 + colg] = f2bf(acc[c][q] * rs[q]);
            }
        }
    }
    __syncthreads();

    stage_B<8>(Tcat + 128 * 128, lds);
    {
        int bf = flags[8];
        f32x4 acc[8];
#pragma unroll
        for (int c = 0; c < 8; ++c) acc[c] = (f32x4){0.f, 0.f, 0.f, 0.f};
#pragma unroll
        for (int kk = 0; kk < 4; ++kk) {
#pragma unroll
            for (int c = 0; c < 8; ++c) {
                bf16x8 b = *(const bf16x8*)&lds[((kk * 8 + c) << 6) + lane];
                acc[c] = __builtin_amdgcn_mfma_f32_16x16x32_bf16(af[kk], b, acc[c], 0, 0, 0);
            }
        }
#pragma unroll
        for (int c = 0; c < 8; ++c) {
            int colg = c * 16 + l16;
            float bv = loadF(bres, colg, bf);
#pragma unroll
            for (int q = 0; q < 4; ++q) {
                int row = row0 + quad * 4 + q;
                if (row < M) Xres[(size_t)row * 128 + colg] = f2bf(acc[c][q] + bv);
            }
        }
    }
}

// ------- aggregation (R15): feature-sliced XCD-affine gather.
// Block = (node-group, slice); slice = bid&3 -> lands on XCD slice / slice+4
// (dispatch round-robins XCDs), so each XCD's gather working set is one
// 32-feature slice = 3.2 MB < 4 MB L2. Wave layout: lane = e4*16 + fl;
// one gather instr fetches 4 edges x 64 B. Edge partials reduced via shfl_xor.
// colw/Out/Xres use nontemporal hints to keep L2 for the H slice. -------
__global__ __launch_bounds__(256) void k_agg(const ushort_t* __restrict__ H,
                                             const int* __restrict__ row_ptr,
                                             const uint_t* __restrict__ colw,
                                             const float* __restrict__ dinv,
                                             const void* __restrict__ bias, int bFid,
                                             const ushort_t* __restrict__ other,
                                             ushort_t* __restrict__ Out,
                                             int n, const int* __restrict__ flags) {
    int s = blockIdx.x & 3;                         // feature slice (XCD-affine)
    int node = (blockIdx.x >> 2) * 4 + (threadIdx.x >> 6);
    if (node >= n) return;
    int lane = threadIdx.x & 63;
    int e4 = lane >> 4;                             // edge sub-lane 0..3
    int fl = lane & 15;                             // feature-pair index 0..15
    int f = s * 32 + fl * 2;
    size_t nidx = (size_t)node * 128 + f;

    int beg = row_ptr[node], end = row_ptr[node + 1];
    float a0 = 0.f, a1 = 0.f;

    for (int bs = beg; bs < end; bs += 64) {
        int rem = end - bs;
        int nb = (rem < 64) ? rem : 64;
        int c = (lane < nb) ? (int)__builtin_nontemporal_load(&colw[bs + lane]) : n;

        for (int j = 0; j < nb; j += 16) {
            int ce[4]; uint_t v[4];
#pragma unroll
            for (int q = 0; q < 4; ++q) ce[q] = __shfl(c, j + q * 4 + e4, 64);
#pragma unroll
            for (int q = 0; q < 4; ++q)
                v[q] = *(const uint_t*)(H + (size_t)ce[q] * 128 + f);
#pragma unroll
            for (int q = 0; q < 4; ++q) {
                a0 += bf2f(v[q] & 0xffffu);
                a1 += bf2f(v[q] >> 16);
            }
        }
    }

    // reduce the 4 edge-sublane partials (lane bits 4,5)
    a0 += __shfl_xor(a0, 16, 64); a1 += __shfl_xor(a1, 16, 64);
    a0 += __shfl_xor(a0, 32, 64); a1 += __shfl_xor(a1, 32, 64);

    if (e4 == 0) {
        uint_t hv = *(const uint_t*)(H + nidx);     // self term H'[node]
        a0 += bf2f(hv & 0xffffu);
        a1 += bf2f(hv >> 16);
        float dv = dinv[node];
        int bfm = flags[bFid];
        float a0o = fmaf(a0, dv, loadF(bias, f, bfm));
        float a1o = fmaf(a1, dv, loadF(bias, f + 1, bfm));
        if (other) {
            uint_t ov = __builtin_nontemporal_load((const uint_t*)(other + nidx));
            a0o += bf2f(ov & 0xffffu);
            a1o += bf2f(ov >> 16);
        }
        a0o = fmaxf(a0o, 0.0f);
        a1o = fmaxf(a1o, 0.0f);
        __builtin_nontemporal_store((uint_t)f2bf(a0o) | ((uint_t)f2bf(a1o) << 16),
                                    (uint_t*)(Out + nidx));
    }
}

// ---------------- launch ----------------

extern "C" void kernel_launch(void* const* d_in, const int* in_sizes, int n_in,
                              void* d_out, int out_size, void* d_ws, size_t ws_size,
                              hipStream_t stream) {
    const int N = in_sizes[0] / 128;
    const int E = in_sizes[1] / 2;

    const void* x  = d_in[0];
    const int*  ei = (const int*)d_in[1];

    char* ws = (char*)d_ws;
    size_t used = 0;
    auto alloc = [&](size_t bytes) {
        char* p = ws + used;
        used += (bytes + 255) & ~(size_t)255;
        return p;
    };

    int*   flags   = (int*)alloc(64 * 4);
    int*   deg     = (int*)alloc((size_t)N * 4);
    int*   row_ptr = (int*)alloc((size_t)(N + 1) * 4);
    float* dinv    = (float*)alloc((size_t)N * 4);
    int2*  tmp     = (int2*)alloc((size_t)E * 8);
    uint_t* colw   = (uint_t*)alloc((size_t)E * 4);
    int*   bsum    = (int*)alloc(256 * 4);
    ushort_t* Tcat = (ushort_t*)alloc(256 * 128 * 2);
    ushort_t* T2   = (ushort_t*)alloc(128 * 128 * 2);
    ushort_t* T3   = (ushort_t*)alloc(128 * 128 * 2);
    ushort_t* Tlin = (ushort_t*)alloc(128 * 64 * 2);

    ushort_t* Hbuf = (ushort_t*)alloc((size_t)(N + 1) * 128 * 2);  // +1 sentinel zero row
    ushort_t* Act1 = (ushort_t*)alloc((size_t)N * 128 * 2);
    ushort_t* Act2 = (ushort_t*)alloc((size_t)N * 128 * 2);
    ushort_t* Xres = (ushort_t*)alloc((size_t)N * 128 * 2);

    if (used > ws_size) return;

    DetectArgs da;
    for (int i = 0; i < 11; ++i) { da.t[i] = d_in[i == 0 ? 0 : i + 1]; da.elems[i] = in_sizes[i == 0 ? 0 : i + 1]; }
    da.ei = ei;
    da.flags = flags;

    const int B = 256;
    int gE4   = ((E + 3) / 4 + B - 1) / B;
    int gPack = (4 * 128 * 128 + 128 * 64) / B;   // 288 blocks = 73728 threads >= N
    int gGemm = (N + 63) / 64;
    int gAgg  = ((N + 3) / 4) * 4;                // (node-group) x (4 feature slices)
    int nb    = (N + 1023) / 1024;                // 49 <= 64 (rowptr self-scan limit)

    uint_t* Hz = (uint_t*)(Hbuf + (size_t)N * 128);

    k_pack<<<gPack, B, 0, stream>>>(da, Tcat, T2, T3, Tlin, deg, N, Hz);
    k_deg<<<gE4, B, 0, stream>>>(ei, E, N, flags, deg, tmp);
    k_bsum<<<nb, B, 0, stream>>>(deg, N, bsum);
    k_rowptr<<<nb, B, 0, stream>>>(deg, bsum, N, row_ptr, dinv);
    k_scatter<<<gE4, B, 0, stream>>>(ei, E, N, flags, row_ptr, tmp, colw);

    // layer 1 (two-phase dual GEMM): H' = (x@W1)*dinv (bf16), Xres = x@Wres + bres (bf16)
    k_gemm_l1<<<gGemm, B, 0, stream>>>(x, Tcat, d_in[9], Hbuf, Xres, N, flags, dinv);
    k_agg<<<gAgg, B, 0, stream>>>(Hbuf, row_ptr, colw, dinv, d_in[3], 2,
                                  Xres, Act1, N, flags);

    // layer 2
    k_gemm2<8><<<gGemm, B, 0, stream>>>(Act1, -1, 1, T2, nullptr, -1, Hbuf, 1, N, flags, dinv);
    k_agg<<<gAgg, B, 0, stream>>>(Hbuf, row_ptr, colw, dinv, d_in[5], 4,
                                  nullptr, Act2, N, flags);

    // layer 3
    k_gemm2<8><<<gGemm, B, 0, stream>>>(Act2, -1, 1, T3, nullptr, -1, Hbuf, 1, N, flags, dinv);
    k_agg<<<gAgg, B, 0, stream>>>(Hbuf, row_ptr, colw, dinv, d_in[7], 6,
                                  nullptr, Act1, N, flags);

    // final: out = Act1@Wlin + blin (fp32 out, no rowscale)
    k_gemm2<4><<<gGemm, B, 0, stream>>>(Act1, -1, 1, Tlin, d_in[11], 10,
                                        d_out, 0, N, flags, nullptr);
}

// Round 4
// 412.269 us; speedup vs baseline: 1.0236x; 1.0236x over previous
//
#include <hip/hip_runtime.h>

typedef unsigned short ushort_t;
typedef unsigned int uint_t;

typedef __bf16 bf16x8 __attribute__((ext_vector_type(8)));
typedef float f32x4 __attribute__((ext_vector_type(4)));

union BFU { ushort_t u; __bf16 h; };

__device__ __forceinline__ float bf2f(uint_t u) {
    union { uint_t i; float f; } v; v.i = u << 16; return v.f;
}
__device__ __forceinline__ ushort_t f2bf(float f) {
    union { float f; uint_t i; } v; v.f = f;
    uint_t r = v.i + 0x7fffu + ((v.i >> 16) & 1u);
    return (ushort_t)(r >> 16);
}
// mode: 1 = bf16 storage, 0 = fp32 storage
__device__ __forceinline__ float loadF(const void* p, size_t i, int isBf16) {
    return isBf16 ? bf2f((uint_t)((const ushort_t*)p)[i]) : ((const float*)p)[i];
}

// flags[0..10]: x,W1,b1,W2,b2,W3,b3,Wres,bres,Wlin,blin  (1=bf16, 0=fp32)
// flags[11]: edge_index is int64 (1) or int32 (0)
struct DetectArgs {
    const void* t[11];
    int elems[11];
    const int* ei;
    int* flags;
};

__device__ __forceinline__ int detect_one(const void* p, int elems) {
    const uint_t* w = (const uint_t*)p;
    int n = elems / 2; if (n > 64) n = 64;
    int cnt = 0;
    for (int k = 0; k < n; ++k) {
        uint_t f = (w[k] >> 7) & 0xFFu;
        cnt += (f >= 100u && f <= 135u);
    }
    return (cnt * 10 >= n * 6) ? 1 : 0;
}

// ---------------- weight pack + dtype detection + deg zeroing ----------------
// Hbuf: planar H' buffer, 4 planes of (N+1) rows x 32 feats; zero sentinel row N of each plane.
__global__ void k_pack(DetectArgs a,
                       ushort_t* __restrict__ Tcat, ushort_t* __restrict__ T2,
                       ushort_t* __restrict__ T3, ushort_t* __restrict__ Tl,
                       int* __restrict__ deg, int N,
                       ushort_t* __restrict__ Hbuf, int hps) {
    __shared__ int lflag;
    int i = blockIdx.x * blockDim.x + threadIdx.x;
    if (i < N) deg[i] = 0;                         // fused memset
    if (blockIdx.x == 1 && threadIdx.x < 64) {     // sentinel rows (4 planes x 64 B)
        int p = threadIdx.x >> 4, w = threadIdx.x & 15;
        ((uint_t*)Hbuf)[(size_t)p * (hps / 2) + (size_t)N * 16 + w] = 0u;
    }
    const int SQ = 128 * 128;
    int m = (i < 4 * SQ) ? (i / SQ) : 4;           // uniform per block (SQ%256==0)
    int fid = (m == 0) ? 1 : (m == 1) ? 3 : (m == 2) ? 5 : (m == 3) ? 7 : 9;
    const void* W = a.t[fid];

    if (threadIdx.x == 0) lflag = detect_one(W, a.elems[fid]);
    if (blockIdx.x == 0 && threadIdx.x >= 64 && threadIdx.x < 75) {
        int t = threadIdx.x - 64;
        a.flags[t] = detect_one(a.t[t], a.elems[t]);
    }
    if (blockIdx.x == 0 && threadIdx.x == 75) {
        int nz = 0;
        for (int k = 0; k < 64; ++k) nz += (a.ei[2 * k + 1] != 0);
        a.flags[11] = (nz == 0) ? 1 : 0;
    }
    __syncthreads();
    int isb = lflag;

    if (i < 4 * SQ) {
        int r = i % SQ;
        int k = r / 128, f = r % 128;
        ushort_t* T = (m == 0) ? Tcat : (m == 1) ? T2 : (m == 2) ? T3 : (Tcat + SQ);
        T[f * 128 + k] = f2bf(loadF(W, (size_t)k * 128 + f, isb));
    } else if (i < 4 * SQ + 128 * 64) {
        int r = i - 4 * SQ;
        int k = r / 64, f = r % 64;
        Tl[f * 128 + k] = f2bf(loadF(W, (size_t)k * 64 + f, isb));
    }
}

// ---------------- degree + rank: the ONLY atomic pass ----------------
__global__ void k_deg(const int* __restrict__ ei, int E, int N,
                      const int* __restrict__ flags, int* __restrict__ deg,
                      int2* __restrict__ tmp) {
    int i = blockIdx.x * blockDim.x + threadIdx.x;
    int e0 = i * 4;
    if (e0 >= E) return;
    int is64 = flags[11];
    if (e0 + 3 < E && (E & 3) == 0) {
        int d[4];
        if (is64) {
            int4 va = *(const int4*)(ei + 2 * E + 2 * e0);
            int4 vb = *(const int4*)(ei + 2 * E + 2 * e0 + 4);
            d[0] = va.x; d[1] = va.z; d[2] = vb.x; d[3] = vb.z;
        } else {
            int4 va = *(const int4*)(ei + E + e0);
            d[0] = va.x; d[1] = va.y; d[2] = va.z; d[3] = va.w;
        }
        int l[4]; bool ok[4];
#pragma unroll
        for (int k = 0; k < 4; ++k) ok[k] = (unsigned)d[k] < (unsigned)N;
#pragma unroll
        for (int k = 0; k < 4; ++k)
            l[k] = ok[k] ? atomicAdd(&deg[d[k]], 1) : 0;
        int4 t01, t23;
        t01.x = ok[0] ? d[0] : -1; t01.y = l[0];
        t01.z = ok[1] ? d[1] : -1; t01.w = l[1];
        t23.x = ok[2] ? d[2] : -1; t23.y = l[2];
        t23.z = ok[3] ? d[3] : -1; t23.w = l[3];
        *(int4*)(tmp + e0) = t01;
        *(int4*)(tmp + e0 + 2) = t23;
    } else {
        for (int e = e0; e < E && e < e0 + 4; ++e) {
            int dd = is64 ? ei[2 * E + 2 * e] : ei[E + e];
            bool ok = (unsigned)dd < (unsigned)N;
            int l = ok ? atomicAdd(&deg[dd], 1) : 0;
            tmp[e] = make_int2(ok ? dd : -1, l);
        }
    }
}

// ---- scan: k_bsum (per-1024-chunk sums) + k_rowptr (self-computed offset) ----

__global__ __launch_bounds__(256) void k_bsum(const int* __restrict__ deg, int n,
                                              int* __restrict__ bsum) {
    int base = blockIdx.x * 1024;
    int local = 0;
#pragma unroll
    for (int j = 0; j < 4; ++j) {
        int idx = base + threadIdx.x + j * 256;
        if (idx < n) local += deg[idx];
    }
    __shared__ int s[4];
#pragma unroll
    for (int off = 32; off; off >>= 1) local += __shfl_down(local, off, 64);
    if ((threadIdx.x & 63) == 0) s[threadIdx.x >> 6] = local;
    __syncthreads();
    if (threadIdx.x == 0) bsum[blockIdx.x] = s[0] + s[1] + s[2] + s[3];
}

// computes own block offset by reducing bsum[0..b-1] (nb <= 64, single wave)
__global__ __launch_bounds__(256) void k_rowptr(const int* __restrict__ deg,
                                                const int* __restrict__ bsum, int n,
                                                int* __restrict__ row_ptr,
                                                float* __restrict__ dinv) {
    __shared__ int s[256];
    __shared__ int sboff;
    int t = threadIdx.x;

    if (t < 64) {
        int v = (t < blockIdx.x) ? bsum[t] : 0;   // exclusive: blocks before me
#pragma unroll
        for (int off = 32; off; off >>= 1) v += __shfl_down(v, off, 64);
        if (t == 0) sboff = v;
    }

    int base = blockIdx.x * 1024 + t * 4;
    int v0 = (base + 0 < n) ? deg[base + 0] : 0;
    int v1 = (base + 1 < n) ? deg[base + 1] : 0;
    int v2 = (base + 2 < n) ? deg[base + 2] : 0;
    int v3 = (base + 3 < n) ? deg[base + 3] : 0;
    int tot = v0 + v1 + v2 + v3;
    s[t] = tot;
    __syncthreads();
    for (int off = 1; off < 256; off <<= 1) {
        int u = (t >= off) ? s[t - off] : 0;
        __syncthreads();
        s[t] += u;
        __syncthreads();
    }
    int run = sboff + ((t == 0) ? 0 : s[t - 1]);
    int vals[4] = {v0, v1, v2, v3};
#pragma unroll
    for (int j = 0; j < 4; ++j) {
        int idx = base + j;
        if (idx < n) {
            row_ptr[idx] = run;
            run += vals[j];
            float df = (float)vals[j] + 1.0f;
            dinv[idx] = rsqrtf(df);
        }
    }
    if (blockIdx.x == gridDim.x - 1 && t == 255) row_ptr[n] = sboff + s[255];
}

// ------- scatter CSR (NO atomics): pos = row_ptr[d] + rank; col only (4B/edge) -------
__global__ void k_scatter(const int* __restrict__ ei, int E, int N,
                          const int* __restrict__ flags,
                          const int* __restrict__ row_ptr,
                          const int2* __restrict__ tmp,
                          uint_t* __restrict__ colw) {
    int i = blockIdx.x * blockDim.x + threadIdx.x;
    int e0 = i * 4;
    if (e0 >= E) return;
    int is64 = flags[11];
    if (e0 + 3 < E && (E & 3) == 0) {
        int s[4];
        if (is64) {
            int4 sa = *(const int4*)(ei + 2 * e0);
            int4 sb = *(const int4*)(ei + 2 * e0 + 4);
            s[0] = sa.x; s[1] = sa.z; s[2] = sb.x; s[3] = sb.z;
        } else {
            int4 sa = *(const int4*)(ei + e0);
            s[0] = sa.x; s[1] = sa.y; s[2] = sa.z; s[3] = sa.w;
        }
        int4 t01 = *(const int4*)(tmp + e0);
        int4 t23 = *(const int4*)(tmp + e0 + 2);
        int d[4] = {t01.x, t01.z, t23.x, t23.z};
        int l[4] = {t01.y, t01.w, t23.y, t23.w};
        int ss[4];
#pragma unroll
        for (int k = 0; k < 4; ++k)
            ss[k] = ((unsigned)s[k] < (unsigned)N) ? s[k] : 0;
#pragma unroll
        for (int k = 0; k < 4; ++k) {
            if (d[k] >= 0)
                colw[row_ptr[d[k]] + l[k]] = (uint_t)ss[k];
        }
    } else {
        for (int e = e0; e < E && e < e0 + 4; ++e) {
            int sv = is64 ? ei[2 * e] : ei[e];
            int2 tv = tmp[e];
            if (tv.x >= 0) {
                int ssv = ((unsigned)sv < (unsigned)N) ? sv : 0;
                colw[row_ptr[tv.x] + tv.y] = (uint_t)ssv;
            }
        }
    }
}

// ===== LDS-staged GEMM, 64 rows/block =====

template <int NCT>
__device__ __forceinline__ void stage_B(const ushort_t* __restrict__ WT, uint4* lds) {
    int t = threadIdx.x;
#pragma unroll
    for (int i = 0; i < NCT; ++i) {
        int g = i * 256 + t;
        uint4 v = ((const uint4*)WT)[g];
        int col = g >> 4, k8 = g & 15;
        int c = col >> 4, l16c = col & 15;
        int kk = k8 >> 2, q = k8 & 3;
        lds[((kk * NCT + c) << 6) + (q << 4) + l16c] = v;
    }
    __syncthreads();
}

// row-major A (input x), fp32 or bf16
__device__ __forceinline__ void load_A1(const void* __restrict__ A, int a16,
                                        int ar, int quad, bf16x8 af[4]) {
    if (a16) {
        const ushort_t* p = (const ushort_t*)A + (size_t)ar * 128 + quad * 8;
#pragma unroll
        for (int kk = 0; kk < 4; ++kk) af[kk] = *(const bf16x8*)(p + kk * 32);
    } else {
        const float* p = (const float*)A + (size_t)ar * 128 + quad * 8;
#pragma unroll
        for (int kk = 0; kk < 4; ++kk) {
            f32x4 u0 = *(const f32x4*)(p + kk * 32);
            f32x4 u1 = *(const f32x4*)(p + kk * 32 + 4);
#pragma unroll
            for (int j = 0; j < 4; ++j) {
                BFU e;
                e.u = f2bf(u0[j]); af[kk][j] = e.h;
                e.u = f2bf(u1[j]); af[kk][j + 4] = e.h;
            }
        }
    }
}

// planar A (4 planes of 32 feats, plane stride aps elems): af[kk] is wholly in plane kk
__device__ __forceinline__ void load_A_planar(const ushort_t* __restrict__ A, int aps,
                                              int ar, int quad, bf16x8 af[4]) {
#pragma unroll
    for (int kk = 0; kk < 4; ++kk)
        af[kk] = *(const bf16x8*)(A + (size_t)kk * aps + (size_t)ar * 32 + quad * 8);
}

// A: planar bf16 (stride aps). C: planar bf16 (cFix=1, plane stride cps) or row-major fp32.
// rowscale != nullptr: C[row] = acc*rowscale[row] (+bias)  -- folds D^-1/2
template <int NCT>
__global__ __launch_bounds__(256, 4) void k_gemm2(const ushort_t* __restrict__ A, int aps,
                                                  const ushort_t* __restrict__ WT,
                                                  const void* __restrict__ bias, int bFid,
                                                  void* __restrict__ C, int cFix, int cps,
                                                  int M, const int* __restrict__ flags,
                                                  const float* __restrict__ rowscale) {
    __shared__ uint4 lds[NCT * 256];
    stage_B<NCT>(WT, lds);

    const int F = NCT * 16;
    int t = threadIdx.x;
    int wave = t >> 6, lane = t & 63;
    int quad = lane >> 4, l16 = lane & 15;
    int row0 = blockIdx.x * 64 + wave * 16;

    int ar = row0 + l16; if (ar >= M) ar = M - 1;

    bf16x8 af[4];
    load_A_planar(A, aps, ar, quad, af);

    f32x4 acc[NCT];
#pragma unroll
    for (int c = 0; c < NCT; ++c) acc[c] = (f32x4){0.f, 0.f, 0.f, 0.f};

#pragma unroll
    for (int kk = 0; kk < 4; ++kk) {
#pragma unroll
        for (int c = 0; c < NCT; ++c) {
            bf16x8 b = *(const bf16x8*)&lds[((kk * NCT + c) << 6) + lane];
            acc[c] = __builtin_amdgcn_mfma_f32_16x16x32_bf16(af[kk], b, acc[c], 0, 0, 0);
        }
    }

    float rs[4];
#pragma unroll
    for (int q = 0; q < 4; ++q) {
        int row = row0 + quad * 4 + q;
        rs[q] = (rowscale && row < M) ? rowscale[row] : 1.0f;
    }

    int bf = (bias && bFid >= 0) ? flags[bFid] : 1;
#pragma unroll
    for (int c = 0; c < NCT; ++c) {
        int colg = c * 16 + l16;
        float bv = bias ? loadF(bias, colg, bf) : 0.0f;
#pragma unroll
        for (int q = 0; q < 4; ++q) {
            int row = row0 + quad * 4 + q;
            if (row < M) {
                float v = acc[c][q] * rs[q] + bv;
                if (cFix) {
                    int p = colg >> 5, po = colg & 31;
                    ((ushort_t*)C)[(size_t)p * cps + (size_t)row * 32 + po] = f2bf(v);
                } else {
                    ((float*)C)[(size_t)row * F + colg] = v;
                }
            }
        }
    }
}

// layer-1 dual output, two-phase staging (32 KB LDS); Hout planar*dinv, Xres planar
__global__ __launch_bounds__(256, 4) void k_gemm_l1(const void* __restrict__ A,
                                                    const ushort_t* __restrict__ Tcat,
                                                    const void* __restrict__ bres,
                                                    ushort_t* __restrict__ Hout, int hps,
                                                    ushort_t* __restrict__ Xres, int xps,
                                                    int M, const int* __restrict__ flags,
                                                    const float* __restrict__ dinv) {
    __shared__ uint4 lds[8 * 256];
    int t = threadIdx.x;
    int wave = t >> 6, lane = t & 63;
    int quad = lane >> 4, l16 = lane & 15;
    int row0 = blockIdx.x * 64 + wave * 16;

    int a16 = flags[0];
    int ar = row0 + l16; if (ar >= M) ar = M - 1;

    bf16x8 af[4];
    load_A1(A, a16, ar, quad, af);

    float rs[4];
#pragma unroll
    for (int q = 0; q < 4; ++q) {
        int row = row0 + quad * 4 + q;
        rs[q] = (row < M) ? dinv[row] : 1.0f;
    }

    stage_B<8>(Tcat, lds);
    {
        f32x4 acc[8];
#pragma unroll
        for (int c = 0; c < 8; ++c) acc[c] = (f32x4){0.f, 0.f, 0.f, 0.f};
#pragma unroll
        for (int kk = 0; kk < 4; ++kk) {
#pragma unroll
            for (int c = 0; c < 8; ++c) {
                bf16x8 b = *(const bf16x8*)&lds[((kk * 8 + c) << 6) + lane];
                acc[c] = __builtin_amdgcn_mfma_f32_16x16x32_bf16(af[kk], b, acc[c], 0, 0, 0);
            }
        }
#pragma unroll
        for (int c = 0; c < 8; ++c) {
            int colg = c * 16 + l16;
            int p = colg >> 5, po = colg & 31;
#pragma unroll
            for (int q = 0; q < 4; ++q) {
                int row = row0 + quad * 4 + q;
                if (row < M)
                    Hout[(size_t)p * hps + (size_t)row * 32 + po] = f2bf(acc[c][q] * rs[q]);
            }
        }
    }
    __syncthreads();

    stage_B<8>(Tcat + 128 * 128, lds);
    {
        int bf = flags[8];
        f32x4 acc[8];
#pragma unroll
        for (int c = 0; c < 8; ++c) acc[c] = (f32x4){0.f, 0.f, 0.f, 0.f};
#pragma unroll
        for (int kk = 0; kk < 4; ++kk) {
#pragma unroll
            for (int c = 0; c < 8; ++c) {
                bf16x8 b = *(const bf16x8*)&lds[((kk * 8 + c) << 6) + lane];
                acc[c] = __builtin_amdgcn_mfma_f32_16x16x32_bf16(af[kk], b, acc[c], 0, 0, 0);
            }
        }
#pragma unroll
        for (int c = 0; c < 8; ++c) {
            int colg = c * 16 + l16;
            int p = colg >> 5, po = colg & 31;
            float bv = loadF(bres, colg, bf);
#pragma unroll
            for (int q = 0; q < 4; ++q) {
                int row = row0 + quad * 4 + q;
                if (row < M)
                    Xres[(size_t)p * xps + (size_t)row * 32 + po] = f2bf(acc[c][q] + bv);
            }
        }
    }
}

// ------- aggregation (R16): planar feature slices, XCD-affine.
// H planar: plane s = contiguous (N+1) x 32 feats (64 B rows) = 3.2 MB < 4 MB L2.
// slice = bid & 3; round-robin dispatch -> XCD k serves only plane k&3.
// Wave: lane = e4*16 + fl; one gather instr = 4 edges x 64 B. Partials via shfl_xor.
// colw/other/Out nontemporal so streams don't evict the plane. -------
__global__ __launch_bounds__(256) void k_agg(const ushort_t* __restrict__ H, int hps,
                                             const int* __restrict__ row_ptr,
                                             const uint_t* __restrict__ colw,
                                             const float* __restrict__ dinv,
                                             const void* __restrict__ bias, int bFid,
                                             const ushort_t* __restrict__ other, int ops,
                                             ushort_t* __restrict__ Out,
                                             int n, const int* __restrict__ flags) {
    int s = blockIdx.x & 3;                         // feature slice (XCD-affine)
    int node = (blockIdx.x >> 2) * 4 + (threadIdx.x >> 6);
    if (node >= n) return;
    int lane = threadIdx.x & 63;
    int e4 = lane >> 4;                             // edge sub-lane 0..3
    int fl = lane & 15;                             // feature-pair index 0..15
    int fo = fl * 2;                                // offset within plane
    const ushort_t* Hs = H + (size_t)s * hps;

    int beg = row_ptr[node], end = row_ptr[node + 1];
    float a0 = 0.f, a1 = 0.f;

    for (int bs = beg; bs < end; bs += 64) {
        int rem = end - bs;
        int nb = (rem < 64) ? rem : 64;
        int c = (lane < nb) ? (int)__builtin_nontemporal_load(&colw[bs + lane]) : n;

        for (int j = 0; j < nb; j += 16) {
            int ce[4]; uint_t v[4];
#pragma unroll
            for (int q = 0; q < 4; ++q) ce[q] = __shfl(c, j + q * 4 + e4, 64);
#pragma unroll
            for (int q = 0; q < 4; ++q)
                v[q] = *(const uint_t*)(Hs + (size_t)ce[q] * 32 + fo);
#pragma unroll
            for (int q = 0; q < 4; ++q) {
                a0 += bf2f(v[q] & 0xffffu);
                a1 += bf2f(v[q] >> 16);
            }
        }
    }

    // reduce the 4 edge-sublane partials (lane bits 4,5)
    a0 += __shfl_xor(a0, 16, 64); a1 += __shfl_xor(a1, 16, 64);
    a0 += __shfl_xor(a0, 32, 64); a1 += __shfl_xor(a1, 32, 64);

    if (e4 == 0) {
        size_t nofs = (size_t)node * 32 + fo;
        uint_t hv = *(const uint_t*)(Hs + nofs);    // self term H'[node]
        a0 += bf2f(hv & 0xffffu);
        a1 += bf2f(hv >> 16);
        float dv = dinv[node];
        int fg = s * 32 + fo;                       // global feature index
        int bfm = flags[bFid];
        float a0o = fmaf(a0, dv, loadF(bias, fg, bfm));
        float a1o = fmaf(a1, dv, loadF(bias, fg + 1, bfm));
        if (other) {
            uint_t ov = __builtin_nontemporal_load(
                (const uint_t*)(other + (size_t)s * ops + nofs));
            a0o += bf2f(ov & 0xffffu);
            a1o += bf2f(ov >> 16);
        }
        a0o = fmaxf(a0o, 0.0f);
        a1o = fmaxf(a1o, 0.0f);
        __builtin_nontemporal_store((uint_t)f2bf(a0o) | ((uint_t)f2bf(a1o) << 16),
                                    (uint_t*)(Out + (size_t)s * ops + nofs));
    }
}

// ---------------- launch ----------------

extern "C" void kernel_launch(void* const* d_in, const int* in_sizes, int n_in,
                              void* d_out, int out_size, void* d_ws, size_t ws_size,
                              hipStream_t stream) {
    const int N = in_sizes[0] / 128;
    const int E = in_sizes[1] / 2;

    const void* x  = d_in[0];
    const int*  ei = (const int*)d_in[1];

    char* ws = (char*)d_ws;
    size_t used = 0;
    auto alloc = [&](size_t bytes) {
        char* p = ws + used;
        used += (bytes + 255) & ~(size_t)255;
        return p;
    };

    int*   flags   = (int*)alloc(64 * 4);
    int*   deg     = (int*)alloc((size_t)N * 4);
    int*   row_ptr = (int*)alloc((size_t)(N + 1) * 4);
    float* dinv    = (float*)alloc((size_t)N * 4);
    int2*  tmp     = (int2*)alloc((size_t)E * 8);
    uint_t* colw   = (uint_t*)alloc((size_t)E * 4);
    int*   bsum    = (int*)alloc(256 * 4);
    ushort_t* Tcat = (ushort_t*)alloc(256 * 128 * 2);
    ushort_t* T2   = (ushort_t*)alloc(128 * 128 * 2);
    ushort_t* T3   = (ushort_t*)alloc(128 * 128 * 2);
    ushort_t* Tlin = (ushort_t*)alloc(128 * 64 * 2);

    ushort_t* Hbuf = (ushort_t*)alloc((size_t)(N + 1) * 128 * 2);  // 4 planes x (N+1) x 32
    ushort_t* Act1 = (ushort_t*)alloc((size_t)N * 128 * 2);        // 4 planes x N x 32
    ushort_t* Act2 = (ushort_t*)alloc((size_t)N * 128 * 2);
    ushort_t* Xres = (ushort_t*)alloc((size_t)N * 128 * 2);

    if (used > ws_size) return;

    const int PH = (N + 1) * 32;   // H plane stride (elems), has sentinel row N
    const int PA = N * 32;         // Act/Xres plane stride (elems)

    DetectArgs da;
    for (int i = 0; i < 11; ++i) { da.t[i] = d_in[i == 0 ? 0 : i + 1]; da.elems[i] = in_sizes[i == 0 ? 0 : i + 1]; }
    da.ei = ei;
    da.flags = flags;

    const int B = 256;
    int gE4   = ((E + 3) / 4 + B - 1) / B;
    int gPack = (4 * 128 * 128 + 128 * 64) / B;   // 288 blocks = 73728 threads >= N
    int gGemm = (N + 63) / 64;
    int gAgg  = ((N + 3) / 4) * 4;                // (node-group) x (4 feature slices)
    int nb    = (N + 1023) / 1024;                // 49 <= 64 (rowptr self-scan limit)

    k_pack<<<gPack, B, 0, stream>>>(da, Tcat, T2, T3, Tlin, deg, N, Hbuf, PH);
    k_deg<<<gE4, B, 0, stream>>>(ei, E, N, flags, deg, tmp);
    k_bsum<<<nb, B, 0, stream>>>(deg, N, bsum);
    k_rowptr<<<nb, B, 0, stream>>>(deg, bsum, N, row_ptr, dinv);
    k_scatter<<<gE4, B, 0, stream>>>(ei, E, N, flags, row_ptr, tmp, colw);

    // layer 1 (two-phase dual GEMM): H' = (x@W1)*dinv (planar), Xres = x@Wres + bres (planar)
    k_gemm_l1<<<gGemm, B, 0, stream>>>(x, Tcat, d_in[9], Hbuf, PH, Xres, PA, N, flags, dinv);
    k_agg<<<gAgg, B, 0, stream>>>(Hbuf, PH, row_ptr, colw, dinv, d_in[3], 2,
                                  Xres, PA, Act1, N, flags);

    // layer 2
    k_gemm2<8><<<gGemm, B, 0, stream>>>(Act1, PA, T2, nullptr, -1, Hbuf, 1, PH, N, flags, dinv);
    k_agg<<<gAgg, B, 0, stream>>>(Hbuf, PH, row_ptr, colw, dinv, d_in[5], 4,
                                  nullptr, PA, Act2, N, flags);

    // layer 3
    k_gemm2<8><<<gGemm, B, 0, stream>>>(Act2, PA, T3, nullptr, -1, Hbuf, 1, PH, N, flags, dinv);
    k_agg<<<gAgg, B, 0, stream>>>(Hbuf, PH, row_ptr, colw, dinv, d_in[7], 6,
                                  nullptr, PA, Act1, N, flags);

    // final: out = Act1@Wlin + blin (fp32 row-major out, no rowscale)
    k_gemm2<4><<<gGemm, B, 0, stream>>>(Act1, PA, Tlin, d_in[11], 10,
                                        d_out, 0, 0, N, flags, nullptr);
}

// Round 5
// 354.562 us; speedup vs baseline: 1.1902x; 1.1628x over previous
//
#include <hip/hip_runtime.h>

typedef unsigned short ushort_t;
typedef unsigned int uint_t;

typedef __bf16 bf16x8 __attribute__((ext_vector_type(8)));
typedef float f32x4 __attribute__((ext_vector_type(4)));

union BFU { ushort_t u; __bf16 h; };

__device__ __forceinline__ float bf2f(uint_t u) {
    union { uint_t i; float f; } v; v.i = u << 16; return v.f;
}
__device__ __forceinline__ ushort_t f2bf(float f) {
    union { float f; uint_t i; } v; v.f = f;
    uint_t r = v.i + 0x7fffu + ((v.i >> 16) & 1u);
    return (ushort_t)(r >> 16);
}
// mode: 1 = bf16 storage, 0 = fp32 storage
__device__ __forceinline__ float loadF(const void* p, size_t i, int isBf16) {
    return isBf16 ? bf2f((uint_t)((const ushort_t*)p)[i]) : ((const float*)p)[i];
}

// flags[0..10]: x,W1,b1,W2,b2,W3,b3,Wres,bres,Wlin,blin  (1=bf16, 0=fp32)
// flags[11]: edge_index is int64 (1) or int32 (0)
struct DetectArgs {
    const void* t[11];
    int elems[11];
    const int* ei;
    int* flags;
};

__device__ __forceinline__ int detect_one(const void* p, int elems) {
    const uint_t* w = (const uint_t*)p;
    int n = elems / 2; if (n > 64) n = 64;
    int cnt = 0;
    for (int k = 0; k < n; ++k) {
        uint_t f = (w[k] >> 7) & 0xFFu;
        cnt += (f >= 100u && f <= 135u);
    }
    return (cnt * 10 >= n * 6) ? 1 : 0;
}

// ---------------- weight pack + dtype detection + deg zeroing ----------------
// Hbuf: planar H' buffer, 4 planes of (N+1) rows x 32 feats; zero sentinel row N of each plane.
__global__ void k_pack(DetectArgs a,
                       ushort_t* __restrict__ Tcat, ushort_t* __restrict__ T2,
                       ushort_t* __restrict__ T3, ushort_t* __restrict__ Tl,
                       int* __restrict__ deg, int N,
                       ushort_t* __restrict__ Hbuf, int hps) {
    __shared__ int lflag;
    int i = blockIdx.x * blockDim.x + threadIdx.x;
    if (i < N) deg[i] = 0;                         // fused memset
    if (blockIdx.x == 1 && threadIdx.x < 64) {     // sentinel rows (4 planes x 64 B)
        int p = threadIdx.x >> 4, w = threadIdx.x & 15;
        ((uint_t*)Hbuf)[(size_t)p * (hps / 2) + (size_t)N * 16 + w] = 0u;
    }
    const int SQ = 128 * 128;
    int m = (i < 4 * SQ) ? (i / SQ) : 4;           // uniform per block (SQ%256==0)
    int fid = (m == 0) ? 1 : (m == 1) ? 3 : (m == 2) ? 5 : (m == 3) ? 7 : 9;
    const void* W = a.t[fid];

    if (threadIdx.x == 0) lflag = detect_one(W, a.elems[fid]);
    if (blockIdx.x == 0 && threadIdx.x >= 64 && threadIdx.x < 75) {
        int t = threadIdx.x - 64;
        a.flags[t] = detect_one(a.t[t], a.elems[t]);
    }
    if (blockIdx.x == 0 && threadIdx.x == 75) {
        int nz = 0;
        for (int k = 0; k < 64; ++k) nz += (a.ei[2 * k + 1] != 0);
        a.flags[11] = (nz == 0) ? 1 : 0;
    }
    __syncthreads();
    int isb = lflag;

    if (i < 4 * SQ) {
        int r = i % SQ;
        int k = r / 128, f = r % 128;
        ushort_t* T = (m == 0) ? Tcat : (m == 1) ? T2 : (m == 2) ? T3 : (Tcat + SQ);
        T[f * 128 + k] = f2bf(loadF(W, (size_t)k * 128 + f, isb));
    } else if (i < 4 * SQ + 128 * 64) {
        int r = i - 4 * SQ;
        int k = r / 64, f = r % 64;
        Tl[f * 128 + k] = f2bf(loadF(W, (size_t)k * 64 + f, isb));
    }
}

// ---------------- degree + rank: the ONLY atomic pass ----------------
__global__ void k_deg(const int* __restrict__ ei, int E, int N,
                      const int* __restrict__ flags, int* __restrict__ deg,
                      int2* __restrict__ tmp) {
    int i = blockIdx.x * blockDim.x + threadIdx.x;
    int e0 = i * 4;
    if (e0 >= E) return;
    int is64 = flags[11];
    if (e0 + 3 < E && (E & 3) == 0) {
        int d[4];
        if (is64) {
            int4 va = *(const int4*)(ei + 2 * E + 2 * e0);
            int4 vb = *(const int4*)(ei + 2 * E + 2 * e0 + 4);
            d[0] = va.x; d[1] = va.z; d[2] = vb.x; d[3] = vb.z;
        } else {
            int4 va = *(const int4*)(ei + E + e0);
            d[0] = va.x; d[1] = va.y; d[2] = va.z; d[3] = va.w;
        }
        int l[4]; bool ok[4];
#pragma unroll
        for (int k = 0; k < 4; ++k) ok[k] = (unsigned)d[k] < (unsigned)N;
#pragma unroll
        for (int k = 0; k < 4; ++k)
            l[k] = ok[k] ? atomicAdd(&deg[d[k]], 1) : 0;
        int4 t01, t23;
        t01.x = ok[0] ? d[0] : -1; t01.y = l[0];
        t01.z = ok[1] ? d[1] : -1; t01.w = l[1];
        t23.x = ok[2] ? d[2] : -1; t23.y = l[2];
        t23.z = ok[3] ? d[3] : -1; t23.w = l[3];
        *(int4*)(tmp + e0) = t01;
        *(int4*)(tmp + e0 + 2) = t23;
    } else {
        for (int e = e0; e < E && e < e0 + 4; ++e) {
            int dd = is64 ? ei[2 * E + 2 * e] : ei[E + e];
            bool ok = (unsigned)dd < (unsigned)N;
            int l = ok ? atomicAdd(&deg[dd], 1) : 0;
            tmp[e] = make_int2(ok ? dd : -1, l);
        }
    }
}

// ---- scan: k_bsum (per-1024-chunk sums) + k_rowptr (self-computed offset) ----

__global__ __launch_bounds__(256) void k_bsum(const int* __restrict__ deg, int n,
                                              int* __restrict__ bsum) {
    int base = blockIdx.x * 1024;
    int local = 0;
#pragma unroll
    for (int j = 0; j < 4; ++j) {
        int idx = base + threadIdx.x + j * 256;
        if (idx < n) local += deg[idx];
    }
    __shared__ int s[4];
#pragma unroll
    for (int off = 32; off; off >>= 1) local += __shfl_down(local, off, 64);
    if ((threadIdx.x & 63) == 0) s[threadIdx.x >> 6] = local;
    __syncthreads();
    if (threadIdx.x == 0) bsum[blockIdx.x] = s[0] + s[1] + s[2] + s[3];
}

// computes own block offset by reducing bsum[0..b-1] (nb <= 64, single wave)
__global__ __launch_bounds__(256) void k_rowptr(const int* __restrict__ deg,
                                                const int* __restrict__ bsum, int n,
                                                int* __restrict__ row_ptr,
                                                float* __restrict__ dinv) {
    __shared__ int s[256];
    __shared__ int sboff;
    int t = threadIdx.x;

    if (t < 64) {
        int v = (t < blockIdx.x) ? bsum[t] : 0;   // exclusive: blocks before me
#pragma unroll
        for (int off = 32; off; off >>= 1) v += __shfl_down(v, off, 64);
        if (t == 0) sboff = v;
    }

    int base = blockIdx.x * 1024 + t * 4;
    int v0 = (base + 0 < n) ? deg[base + 0] : 0;
    int v1 = (base + 1 < n) ? deg[base + 1] : 0;
    int v2 = (base + 2 < n) ? deg[base + 2] : 0;
    int v3 = (base + 3 < n) ? deg[base + 3] : 0;
    int tot = v0 + v1 + v2 + v3;
    s[t] = tot;
    __syncthreads();
    for (int off = 1; off < 256; off <<= 1) {
        int u = (t >= off) ? s[t - off] : 0;
        __syncthreads();
        s[t] += u;
        __syncthreads();
    }
    int run = sboff + ((t == 0) ? 0 : s[t - 1]);
    int vals[4] = {v0, v1, v2, v3};
#pragma unroll
    for (int j = 0; j < 4; ++j) {
        int idx = base + j;
        if (idx < n) {
            row_ptr[idx] = run;
            run += vals[j];
            float df = (float)vals[j] + 1.0f;
            dinv[idx] = rsqrtf(df);
        }
    }
    if (blockIdx.x == gridDim.x - 1 && t == 255) row_ptr[n] = sboff + s[255];
}

// ------- scatter CSR (NO atomics): pos = row_ptr[d] + rank; col only (4B/edge) -------
__global__ void k_scatter(const int* __restrict__ ei, int E, int N,
                          const int* __restrict__ flags,
                          const int* __restrict__ row_ptr,
                          const int2* __restrict__ tmp,
                          uint_t* __restrict__ colw) {
    int i = blockIdx.x * blockDim.x + threadIdx.x;
    int e0 = i * 4;
    if (e0 >= E) return;
    int is64 = flags[11];
    if (e0 + 3 < E && (E & 3) == 0) {
        int s[4];
        if (is64) {
            int4 sa = *(const int4*)(ei + 2 * e0);
            int4 sb = *(const int4*)(ei + 2 * e0 + 4);
            s[0] = sa.x; s[1] = sa.z; s[2] = sb.x; s[3] = sb.z;
        } else {
            int4 sa = *(const int4*)(ei + e0);
            s[0] = sa.x; s[1] = sa.y; s[2] = sa.z; s[3] = sa.w;
        }
        int4 t01 = *(const int4*)(tmp + e0);
        int4 t23 = *(const int4*)(tmp + e0 + 2);
        int d[4] = {t01.x, t01.z, t23.x, t23.z};
        int l[4] = {t01.y, t01.w, t23.y, t23.w};
        int ss[4];
#pragma unroll
        for (int k = 0; k < 4; ++k)
            ss[k] = ((unsigned)s[k] < (unsigned)N) ? s[k] : 0;
#pragma unroll
        for (int k = 0; k < 4; ++k) {
            if (d[k] >= 0)
                colw[row_ptr[d[k]] + l[k]] = (uint_t)ss[k];
        }
    } else {
        for (int e = e0; e < E && e < e0 + 4; ++e) {
            int sv = is64 ? ei[2 * e] : ei[e];
            int2 tv = tmp[e];
            if (tv.x >= 0) {
                int ssv = ((unsigned)sv < (unsigned)N) ? sv : 0;
                colw[row_ptr[tv.x] + tv.y] = (uint_t)ssv;
            }
        }
    }
}

// ===== LDS-staged GEMM, 64 rows/block =====

template <int NCT>
__device__ __forceinline__ void stage_B(const ushort_t* __restrict__ WT, uint4* lds) {
    int t = threadIdx.x;
#pragma unroll
    for (int i = 0; i < NCT; ++i) {
        int g = i * 256 + t;
        uint4 v = ((const uint4*)WT)[g];
        int col = g >> 4, k8 = g & 15;
        int c = col >> 4, l16c = col & 15;
        int kk = k8 >> 2, q = k8 & 3;
        lds[((kk * NCT + c) << 6) + (q << 4) + l16c] = v;
    }
    __syncthreads();
}

// row-major A (input x), fp32 or bf16
__device__ __forceinline__ void load_A1(const void* __restrict__ A, int a16,
                                        int ar, int quad, bf16x8 af[4]) {
    if (a16) {
        const ushort_t* p = (const ushort_t*)A + (size_t)ar * 128 + quad * 8;
#pragma unroll
        for (int kk = 0; kk < 4; ++kk) af[kk] = *(const bf16x8*)(p + kk * 32);
    } else {
        const float* p = (const float*)A + (size_t)ar * 128 + quad * 8;
#pragma unroll
        for (int kk = 0; kk < 4; ++kk) {
            f32x4 u0 = *(const f32x4*)(p + kk * 32);
            f32x4 u1 = *(const f32x4*)(p + kk * 32 + 4);
#pragma unroll
            for (int j = 0; j < 4; ++j) {
                BFU e;
                e.u = f2bf(u0[j]); af[kk][j] = e.h;
                e.u = f2bf(u1[j]); af[kk][j + 4] = e.h;
            }
        }
    }
}

// planar A (4 planes of 32 feats, plane stride aps elems): af[kk] is wholly in plane kk
__device__ __forceinline__ void load_A_planar(const ushort_t* __restrict__ A, int aps,
                                              int ar, int quad, bf16x8 af[4]) {
#pragma unroll
    for (int kk = 0; kk < 4; ++kk)
        af[kk] = *(const bf16x8*)(A + (size_t)kk * aps + (size_t)ar * 32 + quad * 8);
}

// A: planar bf16 (stride aps). C: planar bf16 (cFix=1, plane stride cps) or row-major fp32.
// rowscale != nullptr: C[row] = acc*rowscale[row] (+bias)  -- folds D^-1/2
template <int NCT>
__global__ __launch_bounds__(256, 4) void k_gemm2(const ushort_t* __restrict__ A, int aps,
                                                  const ushort_t* __restrict__ WT,
                                                  const void* __restrict__ bias, int bFid,
                                                  void* __restrict__ C, int cFix, int cps,
                                                  int M, const int* __restrict__ flags,
                                                  const float* __restrict__ rowscale) {
    __shared__ uint4 lds[NCT * 256];
    stage_B<NCT>(WT, lds);

    const int F = NCT * 16;
    int t = threadIdx.x;
    int wave = t >> 6, lane = t & 63;
    int quad = lane >> 4, l16 = lane & 15;
    int row0 = blockIdx.x * 64 + wave * 16;

    int ar = row0 + l16; if (ar >= M) ar = M - 1;

    bf16x8 af[4];
    load_A_planar(A, aps, ar, quad, af);

    f32x4 acc[NCT];
#pragma unroll
    for (int c = 0; c < NCT; ++c) acc[c] = (f32x4){0.f, 0.f, 0.f, 0.f};

#pragma unroll
    for (int kk = 0; kk < 4; ++kk) {
#pragma unroll
        for (int c = 0; c < NCT; ++c) {
            bf16x8 b = *(const bf16x8*)&lds[((kk * NCT + c) << 6) + lane];
            acc[c] = __builtin_amdgcn_mfma_f32_16x16x32_bf16(af[kk], b, acc[c], 0, 0, 0);
        }
    }

    float rs[4];
#pragma unroll
    for (int q = 0; q < 4; ++q) {
        int row = row0 + quad * 4 + q;
        rs[q] = (rowscale && row < M) ? rowscale[row] : 1.0f;
    }

    int bf = (bias && bFid >= 0) ? flags[bFid] : 1;
#pragma unroll
    for (int c = 0; c < NCT; ++c) {
        int colg = c * 16 + l16;
        float bv = bias ? loadF(bias, colg, bf) : 0.0f;
#pragma unroll
        for (int q = 0; q < 4; ++q) {
            int row = row0 + quad * 4 + q;
            if (row < M) {
                float v = acc[c][q] * rs[q] + bv;
                if (cFix) {
                    int p = colg >> 5, po = colg & 31;
                    ((ushort_t*)C)[(size_t)p * cps + (size_t)row * 32 + po] = f2bf(v);
                } else {
                    ((float*)C)[(size_t)row * F + colg] = v;
                }
            }
        }
    }
}

// layer-1 dual output, two-phase staging (32 KB LDS); Hout planar*dinv, Xres planar
__global__ __launch_bounds__(256, 4) void k_gemm_l1(const void* __restrict__ A,
                                                    const ushort_t* __restrict__ Tcat,
                                                    const void* __restrict__ bres,
                                                    ushort_t* __restrict__ Hout, int hps,
                                                    ushort_t* __restrict__ Xres, int xps,
                                                    int M, const int* __restrict__ flags,
                                                    const float* __restrict__ dinv) {
    __shared__ uint4 lds[8 * 256];
    int t = threadIdx.x;
    int wave = t >> 6, lane = t & 63;
    int quad = lane >> 4, l16 = lane & 15;
    int row0 = blockIdx.x * 64 + wave * 16;

    int a16 = flags[0];
    int ar = row0 + l16; if (ar >= M) ar = M - 1;

    bf16x8 af[4];
    load_A1(A, a16, ar, quad, af);

    float rs[4];
#pragma unroll
    for (int q = 0; q < 4; ++q) {
        int row = row0 + quad * 4 + q;
        rs[q] = (row < M) ? dinv[row] : 1.0f;
    }

    stage_B<8>(Tcat, lds);
    {
        f32x4 acc[8];
#pragma unroll
        for (int c = 0; c < 8; ++c) acc[c] = (f32x4){0.f, 0.f, 0.f, 0.f};
#pragma unroll
        for (int kk = 0; kk < 4; ++kk) {
#pragma unroll
            for (int c = 0; c < 8; ++c) {
                bf16x8 b = *(const bf16x8*)&lds[((kk * 8 + c) << 6) + lane];
                acc[c] = __builtin_amdgcn_mfma_f32_16x16x32_bf16(af[kk], b, acc[c], 0, 0, 0);
            }
        }
#pragma unroll
        for (int c = 0; c < 8; ++c) {
            int colg = c * 16 + l16;
            int p = colg >> 5, po = colg & 31;
#pragma unroll
            for (int q = 0; q < 4; ++q) {
                int row = row0 + quad * 4 + q;
                if (row < M)
                    Hout[(size_t)p * hps + (size_t)row * 32 + po] = f2bf(acc[c][q] * rs[q]);
            }
        }
    }
    __syncthreads();

    stage_B<8>(Tcat + 128 * 128, lds);
    {
        int bf = flags[8];
        f32x4 acc[8];
#pragma unroll
        for (int c = 0; c < 8; ++c) acc[c] = (f32x4){0.f, 0.f, 0.f, 0.f};
#pragma unroll
        for (int kk = 0; kk < 4; ++kk) {
#pragma unroll
            for (int c = 0; c < 8; ++c) {
                bf16x8 b = *(const bf16x8*)&lds[((kk * 8 + c) << 6) + lane];
                acc[c] = __builtin_amdgcn_mfma_f32_16x16x32_bf16(af[kk], b, acc[c], 0, 0, 0);
            }
        }
#pragma unroll
        for (int c = 0; c < 8; ++c) {
            int colg = c * 16 + l16;
            int p = colg >> 5, po = colg & 31;
            float bv = loadF(bres, colg, bf);
#pragma unroll
            for (int q = 0; q < 4; ++q) {
                int row = row0 + quad * 4 + q;
                if (row < M)
                    Xres[(size_t)p * xps + (size_t)row * 32 + po] = f2bf(acc[c][q] + bv);
            }
        }
    }
}

// ------- aggregation (R17): planar XCD-affine slices + 4 nodes per wave.
// One wave handles 4 consecutive nodes of one 32-feat slice. Their CSR edge
// ranges are contiguous -> ONE coalesced colw load covers ~51 edges; row_ptr
// boundaries hoisted to SGPRs via readlane (scalar loop bounds). 16-lane group
// e4 gathers edge j+e4's 64 B slice-row; per-node partials reduced with 2
// shfl_xor; epilogue done in parallel, one node per 16-lane group. -------
__global__ __launch_bounds__(256) void k_agg(const ushort_t* __restrict__ H, int hps,
                                             const int* __restrict__ row_ptr,
                                             const uint_t* __restrict__ colw,
                                             const float* __restrict__ dinv,
                                             const void* __restrict__ bias, int bFid,
                                             const ushort_t* __restrict__ other, int ops,
                                             ushort_t* __restrict__ Out,
                                             int n, const int* __restrict__ flags) {
    int s = blockIdx.x & 3;                          // feature slice (XCD-affine)
    int wave = threadIdx.x >> 6;
    int g4 = (blockIdx.x >> 2) * 16 + wave * 4;      // first node of this wave
    if (g4 >= n) return;
    int lane = threadIdx.x & 63;
    int e4 = lane >> 4;                              // 16-lane group 0..3
    int fl = lane & 15;
    int fo = fl * 2;                                 // feat-pair offset in plane
    const ushort_t* Hs = H + (size_t)s * hps;

    // row_ptr[g4..g4+4] -> SGPRs (scalar loop bounds)
    int li = g4 + (lane < 4 ? lane : 4);
    if (li > n) li = n;
    int rpv = row_ptr[li];
    int rp0 = __builtin_amdgcn_readlane(rpv, 0);
    int rp1 = __builtin_amdgcn_readlane(rpv, 1);
    int rp2 = __builtin_amdgcn_readlane(rpv, 2);
    int rp3 = __builtin_amdgcn_readlane(rpv, 3);
    int rp4 = __builtin_amdgcn_readlane(rpv, 4);
    int total = rp4 - rp0;

    float a00 = 0.f, a10 = 0.f, a01 = 0.f, a11 = 0.f;
    float a02 = 0.f, a12 = 0.f, a03 = 0.f, a13 = 0.f;

    for (int wb = 0; wb < total; wb += 64) {
        int cIdx = wb + lane;
        int c = (cIdx < total) ? (int)__builtin_nontemporal_load(&colw[rp0 + cIdx]) : n;

#define NODE_K(RK, RK1, A0, A1)                                            \
        {                                                                  \
            int lo = RK - rp0 - wb; if (lo < 0) lo = 0;                    \
            int hi = RK1 - rp0 - wb; if (hi > 64) hi = 64;                 \
            for (int j = lo; j < hi; j += 4) {                             \
                int idx = j + e4;                                          \
                int ce = __shfl(c, idx, 64);                               \
                if (idx >= hi) ce = n;                                     \
                uint_t v = *(const uint_t*)(Hs + (size_t)ce * 32 + fo);    \
                A0 += bf2f(v & 0xffffu);                                   \
                A1 += bf2f(v >> 16);                                       \
            }                                                              \
        }
        NODE_K(rp0, rp1, a00, a10)
        NODE_K(rp1, rp2, a01, a11)
        NODE_K(rp2, rp3, a02, a12)
        NODE_K(rp3, rp4, a03, a13)
#undef NODE_K
    }

    // reduce the 4 edge-sublane partials (lane bits 4,5) for each node
    a00 += __shfl_xor(a00, 16, 64); a00 += __shfl_xor(a00, 32, 64);
    a10 += __shfl_xor(a10, 16, 64); a10 += __shfl_xor(a10, 32, 64);
    a01 += __shfl_xor(a01, 16, 64); a01 += __shfl_xor(a01, 32, 64);
    a11 += __shfl_xor(a11, 16, 64); a11 += __shfl_xor(a11, 32, 64);
    a02 += __shfl_xor(a02, 16, 64); a02 += __shfl_xor(a02, 32, 64);
    a12 += __shfl_xor(a12, 16, 64); a12 += __shfl_xor(a12, 32, 64);
    a03 += __shfl_xor(a03, 16, 64); a03 += __shfl_xor(a03, 32, 64);
    a13 += __shfl_xor(a13, 16, 64); a13 += __shfl_xor(a13, 32, 64);

    // group e4 finishes node g4+e4 (all 64 lanes active in epilogue)
    float A0 = (e4 == 0) ? a00 : (e4 == 1) ? a01 : (e4 == 2) ? a02 : a03;
    float A1 = (e4 == 0) ? a10 : (e4 == 1) ? a11 : (e4 == 2) ? a12 : a13;
    int nk = g4 + e4;
    if (nk < n) {
        size_t nofs = (size_t)nk * 32 + fo;
        uint_t hv = *(const uint_t*)(Hs + nofs);     // self term H'[node]
        A0 += bf2f(hv & 0xffffu);
        A1 += bf2f(hv >> 16);
        float dv = dinv[nk];
        int fg = s * 32 + fo;                        // global feature index
        int bfm = flags[bFid];
        float a0o = fmaf(A0, dv, loadF(bias, fg, bfm));
        float a1o = fmaf(A1, dv, loadF(bias, fg + 1, bfm));
        if (other) {
            uint_t ov = __builtin_nontemporal_load(
                (const uint_t*)(other + (size_t)s * ops + nofs));
            a0o += bf2f(ov & 0xffffu);
            a1o += bf2f(ov >> 16);
        }
        a0o = fmaxf(a0o, 0.0f);
        a1o = fmaxf(a1o, 0.0f);
        __builtin_nontemporal_store((uint_t)f2bf(a0o) | ((uint_t)f2bf(a1o) << 16),
                                    (uint_t*)(Out + (size_t)s * ops + nofs));
    }
}

// ---------------- launch ----------------

extern "C" void kernel_launch(void* const* d_in, const int* in_sizes, int n_in,
                              void* d_out, int out_size, void* d_ws, size_t ws_size,
                              hipStream_t stream) {
    const int N = in_sizes[0] / 128;
    const int E = in_sizes[1] / 2;

    const void* x  = d_in[0];
    const int*  ei = (const int*)d_in[1];

    char* ws = (char*)d_ws;
    size_t used = 0;
    auto alloc = [&](size_t bytes) {
        char* p = ws + used;
        used += (bytes + 255) & ~(size_t)255;
        return p;
    };

    int*   flags   = (int*)alloc(64 * 4);
    int*   deg     = (int*)alloc((size_t)N * 4);
    int*   row_ptr = (int*)alloc((size_t)(N + 1) * 4);
    float* dinv    = (float*)alloc((size_t)N * 4);
    int2*  tmp     = (int2*)alloc((size_t)E * 8);
    uint_t* colw   = (uint_t*)alloc((size_t)E * 4);
    int*   bsum    = (int*)alloc(256 * 4);
    ushort_t* Tcat = (ushort_t*)alloc(256 * 128 * 2);
    ushort_t* T2   = (ushort_t*)alloc(128 * 128 * 2);
    ushort_t* T3   = (ushort_t*)alloc(128 * 128 * 2);
    ushort_t* Tlin = (ushort_t*)alloc(128 * 64 * 2);

    ushort_t* Hbuf = (ushort_t*)alloc((size_t)(N + 1) * 128 * 2);  // 4 planes x (N+1) x 32
    ushort_t* Act1 = (ushort_t*)alloc((size_t)N * 128 * 2);        // 4 planes x N x 32
    ushort_t* Act2 = (ushort_t*)alloc((size_t)N * 128 * 2);
    ushort_t* Xres = (ushort_t*)alloc((size_t)N * 128 * 2);

    if (used > ws_size) return;

    const int PH = (N + 1) * 32;   // H plane stride (elems), has sentinel row N
    const int PA = N * 32;         // Act/Xres plane stride (elems)

    DetectArgs da;
    for (int i = 0; i < 11; ++i) { da.t[i] = d_in[i == 0 ? 0 : i + 1]; da.elems[i] = in_sizes[i == 0 ? 0 : i + 1]; }
    da.ei = ei;
    da.flags = flags;

    const int B = 256;
    int gE4   = ((E + 3) / 4 + B - 1) / B;
    int gPack = (4 * 128 * 128 + 128 * 64) / B;   // 288 blocks = 73728 threads >= N
    int gGemm = (N + 63) / 64;
    int gAgg  = ((N + 15) / 16) * 4;              // (16-node groups) x (4 slices)
    int nb    = (N + 1023) / 1024;                // 49 <= 64 (rowptr self-scan limit)

    k_pack<<<gPack, B, 0, stream>>>(da, Tcat, T2, T3, Tlin, deg, N, Hbuf, PH);
    k_deg<<<gE4, B, 0, stream>>>(ei, E, N, flags, deg, tmp);
    k_bsum<<<nb, B, 0, stream>>>(deg, N, bsum);
    k_rowptr<<<nb, B, 0, stream>>>(deg, bsum, N, row_ptr, dinv);
    k_scatter<<<gE4, B, 0, stream>>>(ei, E, N, flags, row_ptr, tmp, colw);

    // layer 1 (two-phase dual GEMM): H' = (x@W1)*dinv (planar), Xres = x@Wres + bres (planar)
    k_gemm_l1<<<gGemm, B, 0, stream>>>(x, Tcat, d_in[9], Hbuf, PH, Xres, PA, N, flags, dinv);
    k_agg<<<gAgg, B, 0, stream>>>(Hbuf, PH, row_ptr, colw, dinv, d_in[3], 2,
                                  Xres, PA, Act1, N, flags);

    // layer 2
    k_gemm2<8><<<gGemm, B, 0, stream>>>(Act1, PA, T2, nullptr, -1, Hbuf, 1, PH, N, flags, dinv);
    k_agg<<<gAgg, B, 0, stream>>>(Hbuf, PH, row_ptr, colw, dinv, d_in[5], 4,
                                  nullptr, PA, Act2, N, flags);

    // layer 3
    k_gemm2<8><<<gGemm, B, 0, stream>>>(Act2, PA, T3, nullptr, -1, Hbuf, 1, PH, N, flags, dinv);
    k_agg<<<gAgg, B, 0, stream>>>(Hbuf, PH, row_ptr, colw, dinv, d_in[7], 6,
                                  nullptr, PA, Act1, N, flags);

    // final: out = Act1@Wlin + blin (fp32 row-major out, no rowscale)
    k_gemm2<4><<<gGemm, B, 0, stream>>>(Act1, PA, Tlin, d_in[11], 10,
                                        d_out, 0, 0, N, flags, nullptr);
}

// Round 6
// 306.755 us; speedup vs baseline: 1.3757x; 1.1558x over previous
//
#include <hip/hip_runtime.h>

typedef unsigned short ushort_t;
typedef unsigned int uint_t;

typedef __bf16 bf16x8 __attribute__((ext_vector_type(8)));
typedef float f32x4 __attribute__((ext_vector_type(4)));

union BFU { ushort_t u; __bf16 h; };

__device__ __forceinline__ float bf2f(uint_t u) {
    union { uint_t i; float f; } v; v.i = u << 16; return v.f;
}
__device__ __forceinline__ ushort_t f2bf(float f) {
    union { float f; uint_t i; } v; v.f = f;
    uint_t r = v.i + 0x7fffu + ((v.i >> 16) & 1u);
    return (ushort_t)(r >> 16);
}
// mode: 1 = bf16 storage, 0 = fp32 storage
__device__ __forceinline__ float loadF(const void* p, size_t i, int isBf16) {
    return isBf16 ? bf2f((uint_t)((const ushort_t*)p)[i]) : ((const float*)p)[i];
}

// flags[0..10]: x,W1,b1,W2,b2,W3,b3,Wres,bres,Wlin,blin  (1=bf16, 0=fp32)
// flags[11]: edge_index is int64 (1) or int32 (0)
struct DetectArgs {
    const void* t[11];
    int elems[11];
    const int* ei;
    int* flags;
};

__device__ __forceinline__ int detect_one(const void* p, int elems) {
    const uint_t* w = (const uint_t*)p;
    int n = elems / 2; if (n > 64) n = 64;
    int cnt = 0;
    for (int k = 0; k < n; ++k) {
        uint_t f = (w[k] >> 7) & 0xFFu;
        cnt += (f >= 100u && f <= 135u);
    }
    return (cnt * 10 >= n * 6) ? 1 : 0;
}

// ---------------- weight pack + dtype detection + deg zeroing ----------------
// Hbuf: planar H' buffer, 4 planes of (N+1) rows x 32 feats; zero sentinel row N of each plane.
__global__ void k_pack(DetectArgs a,
                       ushort_t* __restrict__ Tcat, ushort_t* __restrict__ T2,
                       ushort_t* __restrict__ T3, ushort_t* __restrict__ Tl,
                       int* __restrict__ deg, int N,
                       ushort_t* __restrict__ Hbuf, int hps) {
    __shared__ int lflag;
    int i = blockIdx.x * blockDim.x + threadIdx.x;
    if (i < N) deg[i] = 0;                         // fused memset
    if (blockIdx.x == 1 && threadIdx.x < 64) {     // sentinel rows (4 planes x 64 B)
        int p = threadIdx.x >> 4, w = threadIdx.x & 15;
        ((uint_t*)Hbuf)[(size_t)p * (hps / 2) + (size_t)N * 16 + w] = 0u;
    }
    const int SQ = 128 * 128;
    int m = (i < 4 * SQ) ? (i / SQ) : 4;           // uniform per block (SQ%256==0)
    int fid = (m == 0) ? 1 : (m == 1) ? 3 : (m == 2) ? 5 : (m == 3) ? 7 : 9;
    const void* W = a.t[fid];

    if (threadIdx.x == 0) lflag = detect_one(W, a.elems[fid]);
    if (blockIdx.x == 0 && threadIdx.x >= 64 && threadIdx.x < 75) {
        int t = threadIdx.x - 64;
        a.flags[t] = detect_one(a.t[t], a.elems[t]);
    }
    if (blockIdx.x == 0 && threadIdx.x == 75) {
        int nz = 0;
        for (int k = 0; k < 64; ++k) nz += (a.ei[2 * k + 1] != 0);
        a.flags[11] = (nz == 0) ? 1 : 0;
    }
    __syncthreads();
    int isb = lflag;

    if (i < 4 * SQ) {
        int r = i % SQ;
        int k = r / 128, f = r % 128;
        ushort_t* T = (m == 0) ? Tcat : (m == 1) ? T2 : (m == 2) ? T3 : (Tcat + SQ);
        T[f * 128 + k] = f2bf(loadF(W, (size_t)k * 128 + f, isb));
    } else if (i < 4 * SQ + 128 * 64) {
        int r = i - 4 * SQ;
        int k = r / 64, f = r % 64;
        Tl[f * 128 + k] = f2bf(loadF(W, (size_t)k * 64 + f, isb));
    }
}

// ---------------- degree + rank: the ONLY atomic pass ----------------
__global__ void k_deg(const int* __restrict__ ei, int E, int N,
                      const int* __restrict__ flags, int* __restrict__ deg,
                      int2* __restrict__ tmp) {
    int i = blockIdx.x * blockDim.x + threadIdx.x;
    int e0 = i * 4;
    if (e0 >= E) return;
    int is64 = flags[11];
    if (e0 + 3 < E && (E & 3) == 0) {
        int d[4];
        if (is64) {
            int4 va = *(const int4*)(ei + 2 * E + 2 * e0);
            int4 vb = *(const int4*)(ei + 2 * E + 2 * e0 + 4);
            d[0] = va.x; d[1] = va.z; d[2] = vb.x; d[3] = vb.z;
        } else {
            int4 va = *(const int4*)(ei + E + e0);
            d[0] = va.x; d[1] = va.y; d[2] = va.z; d[3] = va.w;
        }
        int l[4]; bool ok[4];
#pragma unroll
        for (int k = 0; k < 4; ++k) ok[k] = (unsigned)d[k] < (unsigned)N;
#pragma unroll
        for (int k = 0; k < 4; ++k)
            l[k] = ok[k] ? atomicAdd(&deg[d[k]], 1) : 0;
        int4 t01, t23;
        t01.x = ok[0] ? d[0] : -1; t01.y = l[0];
        t01.z = ok[1] ? d[1] : -1; t01.w = l[1];
        t23.x = ok[2] ? d[2] : -1; t23.y = l[2];
        t23.z = ok[3] ? d[3] : -1; t23.w = l[3];
        *(int4*)(tmp + e0) = t01;
        *(int4*)(tmp + e0 + 2) = t23;
    } else {
        for (int e = e0; e < E && e < e0 + 4; ++e) {
            int dd = is64 ? ei[2 * E + 2 * e] : ei[E + e];
            bool ok = (unsigned)dd < (unsigned)N;
            int l = ok ? atomicAdd(&deg[dd], 1) : 0;
            tmp[e] = make_int2(ok ? dd : -1, l);
        }
    }
}

// ---- scan: k_bsum (per-1024-chunk sums) + k_rowptr (self-computed offset) ----

__global__ __launch_bounds__(256) void k_bsum(const int* __restrict__ deg, int n,
                                              int* __restrict__ bsum) {
    int base = blockIdx.x * 1024;
    int local = 0;
#pragma unroll
    for (int j = 0; j < 4; ++j) {
        int idx = base + threadIdx.x + j * 256;
        if (idx < n) local += deg[idx];
    }
    __shared__ int s[4];
#pragma unroll
    for (int off = 32; off; off >>= 1) local += __shfl_down(local, off, 64);
    if ((threadIdx.x & 63) == 0) s[threadIdx.x >> 6] = local;
    __syncthreads();
    if (threadIdx.x == 0) bsum[blockIdx.x] = s[0] + s[1] + s[2] + s[3];
}

// computes own block offset by reducing bsum[0..b-1] (nb <= 64, single wave)
__global__ __launch_bounds__(256) void k_rowptr(const int* __restrict__ deg,
                                                const int* __restrict__ bsum, int n,
                                                int* __restrict__ row_ptr,
                                                float* __restrict__ dinv) {
    __shared__ int s[256];
    __shared__ int sboff;
    int t = threadIdx.x;

    if (t < 64) {
        int v = (t < blockIdx.x) ? bsum[t] : 0;   // exclusive: blocks before me
#pragma unroll
        for (int off = 32; off; off >>= 1) v += __shfl_down(v, off, 64);
        if (t == 0) sboff = v;
    }

    int base = blockIdx.x * 1024 + t * 4;
    int v0 = (base + 0 < n) ? deg[base + 0] : 0;
    int v1 = (base + 1 < n) ? deg[base + 1] : 0;
    int v2 = (base + 2 < n) ? deg[base + 2] : 0;
    int v3 = (base + 3 < n) ? deg[base + 3] : 0;
    int tot = v0 + v1 + v2 + v3;
    s[t] = tot;
    __syncthreads();
    for (int off = 1; off < 256; off <<= 1) {
        int u = (t >= off) ? s[t - off] : 0;
        __syncthreads();
        s[t] += u;
        __syncthreads();
    }
    int run = sboff + ((t == 0) ? 0 : s[t - 1]);
    int vals[4] = {v0, v1, v2, v3};
#pragma unroll
    for (int j = 0; j < 4; ++j) {
        int idx = base + j;
        if (idx < n) {
            row_ptr[idx] = run;
            run += vals[j];
            float df = (float)vals[j] + 1.0f;
            dinv[idx] = rsqrtf(df);
        }
    }
    if (blockIdx.x == gridDim.x - 1 && t == 255) row_ptr[n] = sboff + s[255];
}

// ------- scatter CSR (NO atomics): pos = row_ptr[d] + rank; col only (4B/edge) -------
__global__ void k_scatter(const int* __restrict__ ei, int E, int N,
                          const int* __restrict__ flags,
                          const int* __restrict__ row_ptr,
                          const int2* __restrict__ tmp,
                          uint_t* __restrict__ colw) {
    int i = blockIdx.x * blockDim.x + threadIdx.x;
    int e0 = i * 4;
    if (e0 >= E) return;
    int is64 = flags[11];
    if (e0 + 3 < E && (E & 3) == 0) {
        int s[4];
        if (is64) {
            int4 sa = *(const int4*)(ei + 2 * e0);
            int4 sb = *(const int4*)(ei + 2 * e0 + 4);
            s[0] = sa.x; s[1] = sa.z; s[2] = sb.x; s[3] = sb.z;
        } else {
            int4 sa = *(const int4*)(ei + e0);
            s[0] = sa.x; s[1] = sa.y; s[2] = sa.z; s[3] = sa.w;
        }
        int4 t01 = *(const int4*)(tmp + e0);
        int4 t23 = *(const int4*)(tmp + e0 + 2);
        int d[4] = {t01.x, t01.z, t23.x, t23.z};
        int l[4] = {t01.y, t01.w, t23.y, t23.w};
        int ss[4];
#pragma unroll
        for (int k = 0; k < 4; ++k)
            ss[k] = ((unsigned)s[k] < (unsigned)N) ? s[k] : 0;
#pragma unroll
        for (int k = 0; k < 4; ++k) {
            if (d[k] >= 0)
                colw[row_ptr[d[k]] + l[k]] = (uint_t)ss[k];
        }
    } else {
        for (int e = e0; e < E && e < e0 + 4; ++e) {
            int sv = is64 ? ei[2 * e] : ei[e];
            int2 tv = tmp[e];
            if (tv.x >= 0) {
                int ssv = ((unsigned)sv < (unsigned)N) ? sv : 0;
                colw[row_ptr[tv.x] + tv.y] = (uint_t)ssv;
            }
        }
    }
}

// ===== LDS-staged GEMM, 64 rows/block =====

template <int NCT>
__device__ __forceinline__ void stage_B(const ushort_t* __restrict__ WT, uint4* lds) {
    int t = threadIdx.x;
#pragma unroll
    for (int i = 0; i < NCT; ++i) {
        int g = i * 256 + t;
        uint4 v = ((const uint4*)WT)[g];
        int col = g >> 4, k8 = g & 15;
        int c = col >> 4, l16c = col & 15;
        int kk = k8 >> 2, q = k8 & 3;
        lds[((kk * NCT + c) << 6) + (q << 4) + l16c] = v;
    }
    __syncthreads();
}

// row-major A (input x), fp32 or bf16
__device__ __forceinline__ void load_A1(const void* __restrict__ A, int a16,
                                        int ar, int quad, bf16x8 af[4]) {
    if (a16) {
        const ushort_t* p = (const ushort_t*)A + (size_t)ar * 128 + quad * 8;
#pragma unroll
        for (int kk = 0; kk < 4; ++kk) af[kk] = *(const bf16x8*)(p + kk * 32);
    } else {
        const float* p = (const float*)A + (size_t)ar * 128 + quad * 8;
#pragma unroll
        for (int kk = 0; kk < 4; ++kk) {
            f32x4 u0 = *(const f32x4*)(p + kk * 32);
            f32x4 u1 = *(const f32x4*)(p + kk * 32 + 4);
#pragma unroll
            for (int j = 0; j < 4; ++j) {
                BFU e;
                e.u = f2bf(u0[j]); af[kk][j] = e.h;
                e.u = f2bf(u1[j]); af[kk][j + 4] = e.h;
            }
        }
    }
}

// planar A (4 planes of 32 feats, plane stride aps elems): af[kk] is wholly in plane kk
__device__ __forceinline__ void load_A_planar(const ushort_t* __restrict__ A, int aps,
                                              int ar, int quad, bf16x8 af[4]) {
#pragma unroll
    for (int kk = 0; kk < 4; ++kk)
        af[kk] = *(const bf16x8*)(A + (size_t)kk * aps + (size_t)ar * 32 + quad * 8);
}

// A: planar bf16 (stride aps). C: planar bf16 (cFix=1, plane stride cps) or row-major fp32.
// rowscale != nullptr: C[row] = acc*rowscale[row] (+bias)  -- folds D^-1/2
template <int NCT>
__global__ __launch_bounds__(256, 4) void k_gemm2(const ushort_t* __restrict__ A, int aps,
                                                  const ushort_t* __restrict__ WT,
                                                  const void* __restrict__ bias, int bFid,
                                                  void* __restrict__ C, int cFix, int cps,
                                                  int M, const int* __restrict__ flags,
                                                  const float* __restrict__ rowscale) {
    __shared__ uint4 lds[NCT * 256];
    stage_B<NCT>(WT, lds);

    const int F = NCT * 16;
    int t = threadIdx.x;
    int wave = t >> 6, lane = t & 63;
    int quad = lane >> 4, l16 = lane & 15;
    int row0 = blockIdx.x * 64 + wave * 16;

    int ar = row0 + l16; if (ar >= M) ar = M - 1;

    bf16x8 af[4];
    load_A_planar(A, aps, ar, quad, af);

    f32x4 acc[NCT];
#pragma unroll
    for (int c = 0; c < NCT; ++c) acc[c] = (f32x4){0.f, 0.f, 0.f, 0.f};

#pragma unroll
    for (int kk = 0; kk < 4; ++kk) {
#pragma unroll
        for (int c = 0; c < NCT; ++c) {
            bf16x8 b = *(const bf16x8*)&lds[((kk * NCT + c) << 6) + lane];
            acc[c] = __builtin_amdgcn_mfma_f32_16x16x32_bf16(af[kk], b, acc[c], 0, 0, 0);
        }
    }

    float rs[4];
#pragma unroll
    for (int q = 0; q < 4; ++q) {
        int row = row0 + quad * 4 + q;
        rs[q] = (rowscale && row < M) ? rowscale[row] : 1.0f;
    }

    int bf = (bias && bFid >= 0) ? flags[bFid] : 1;
#pragma unroll
    for (int c = 0; c < NCT; ++c) {
        int colg = c * 16 + l16;
        float bv = bias ? loadF(bias, colg, bf) : 0.0f;
#pragma unroll
        for (int q = 0; q < 4; ++q) {
            int row = row0 + quad * 4 + q;
            if (row < M) {
                float v = acc[c][q] * rs[q] + bv;
                if (cFix) {
                    int p = colg >> 5, po = colg & 31;
                    ((ushort_t*)C)[(size_t)p * cps + (size_t)row * 32 + po] = f2bf(v);
                } else {
                    ((float*)C)[(size_t)row * F + colg] = v;
                }
            }
        }
    }
}

// layer-1 dual output, two-phase staging (32 KB LDS); Hout planar*dinv, Xres planar
__global__ __launch_bounds__(256, 4) void k_gemm_l1(const void* __restrict__ A,
                                                    const ushort_t* __restrict__ Tcat,
                                                    const void* __restrict__ bres,
                                                    ushort_t* __restrict__ Hout, int hps,
                                                    ushort_t* __restrict__ Xres, int xps,
                                                    int M, const int* __restrict__ flags,
                                                    const float* __restrict__ dinv) {
    __shared__ uint4 lds[8 * 256];
    int t = threadIdx.x;
    int wave = t >> 6, lane = t & 63;
    int quad = lane >> 4, l16 = lane & 15;
    int row0 = blockIdx.x * 64 + wave * 16;

    int a16 = flags[0];
    int ar = row0 + l16; if (ar >= M) ar = M - 1;

    bf16x8 af[4];
    load_A1(A, a16, ar, quad, af);

    float rs[4];
#pragma unroll
    for (int q = 0; q < 4; ++q) {
        int row = row0 + quad * 4 + q;
        rs[q] = (row < M) ? dinv[row] : 1.0f;
    }

    stage_B<8>(Tcat, lds);
    {
        f32x4 acc[8];
#pragma unroll
        for (int c = 0; c < 8; ++c) acc[c] = (f32x4){0.f, 0.f, 0.f, 0.f};
#pragma unroll
        for (int kk = 0; kk < 4; ++kk) {
#pragma unroll
            for (int c = 0; c < 8; ++c) {
                bf16x8 b = *(const bf16x8*)&lds[((kk * 8 + c) << 6) + lane];
                acc[c] = __builtin_amdgcn_mfma_f32_16x16x32_bf16(af[kk], b, acc[c], 0, 0, 0);
            }
        }
#pragma unroll
        for (int c = 0; c < 8; ++c) {
            int colg = c * 16 + l16;
            int p = colg >> 5, po = colg & 31;
#pragma unroll
            for (int q = 0; q < 4; ++q) {
                int row = row0 + quad * 4 + q;
                if (row < M)
                    Hout[(size_t)p * hps + (size_t)row * 32 + po] = f2bf(acc[c][q] * rs[q]);
            }
        }
    }
    __syncthreads();

    stage_B<8>(Tcat + 128 * 128, lds);
    {
        int bf = flags[8];
        f32x4 acc[8];
#pragma unroll
        for (int c = 0; c < 8; ++c) acc[c] = (f32x4){0.f, 0.f, 0.f, 0.f};
#pragma unroll
        for (int kk = 0; kk < 4; ++kk) {
#pragma unroll
            for (int c = 0; c < 8; ++c) {
                bf16x8 b = *(const bf16x8*)&lds[((kk * 8 + c) << 6) + lane];
                acc[c] = __builtin_amdgcn_mfma_f32_16x16x32_bf16(af[kk], b, acc[c], 0, 0, 0);
            }
        }
#pragma unroll
        for (int c = 0; c < 8; ++c) {
            int colg = c * 16 + l16;
            int p = colg >> 5, po = colg & 31;
            float bv = loadF(bres, colg, bf);
#pragma unroll
            for (int q = 0; q < 4; ++q) {
                int row = row0 + quad * 4 + q;
                if (row < M)
                    Xres[(size_t)p * xps + (size_t)row * 32 + po] = f2bf(acc[c][q] + bv);
            }
        }
    }
}

// ------- aggregation (R18): planar XCD-affine slices + one 16-lane group per node.
// Group e4 owns node g4+e4: loads its own 16 colw entries (64 B coalesced),
// broadcasts via __shfl(c,q,16) in a FULLY UNROLLED 16-deep burst -> 16 gathers
// in flight per lane. Tail edges hit the sentinel zero row (hot line). No
// segmentation, no inter-group reduce; epilogue on all 64 lanes. -------
__global__ __launch_bounds__(256) void k_agg(const ushort_t* __restrict__ H, int hps,
                                             const int* __restrict__ row_ptr,
                                             const uint_t* __restrict__ colw,
                                             const float* __restrict__ dinv,
                                             const void* __restrict__ bias, int bFid,
                                             const ushort_t* __restrict__ other, int ops,
                                             ushort_t* __restrict__ Out,
                                             int n, const int* __restrict__ flags) {
    int s = blockIdx.x & 3;                          // feature slice (XCD-affine)
    int wave = threadIdx.x >> 6;
    int lane = threadIdx.x & 63;
    int e4 = lane >> 4;                              // 16-lane group = one node
    int fl = lane & 15;
    int fo = fl * 2;                                 // feat-pair offset in plane
    int node = (blockIdx.x >> 2) * 16 + wave * 4 + e4;
    bool ok = (node < n);
    const ushort_t* Hs = H + (size_t)s * hps;

    int beg = ok ? row_ptr[node] : 0;
    int end = ok ? row_ptr[node + 1] : 0;

    float a0 = 0.f, a1 = 0.f;

    for (int b = beg; b < end; b += 16) {
        int ci = b + fl;
        int c = (ci < end) ? (int)__builtin_nontemporal_load(&colw[ci]) : n;
#pragma unroll
        for (int q = 0; q < 16; ++q) {
            int ce = __shfl(c, q, 16);               // broadcast within group
            uint_t v = *(const uint_t*)(Hs + (size_t)ce * 32 + fo);
            a0 += bf2f(v & 0xffffu);
            a1 += bf2f(v >> 16);
        }
    }

    if (ok) {
        size_t nofs = (size_t)node * 32 + fo;
        uint_t hv = *(const uint_t*)(Hs + nofs);     // self term H'[node]
        a0 += bf2f(hv & 0xffffu);
        a1 += bf2f(hv >> 16);
        float dv = dinv[node];
        int fg = s * 32 + fo;                        // global feature index
        int bfm = flags[bFid];
        float a0o = fmaf(a0, dv, loadF(bias, fg, bfm));
        float a1o = fmaf(a1, dv, loadF(bias, fg + 1, bfm));
        if (other) {
            uint_t ov = __builtin_nontemporal_load(
                (const uint_t*)(other + (size_t)s * ops + nofs));
            a0o += bf2f(ov & 0xffffu);
            a1o += bf2f(ov >> 16);
        }
        a0o = fmaxf(a0o, 0.0f);
        a1o = fmaxf(a1o, 0.0f);
        __builtin_nontemporal_store((uint_t)f2bf(a0o) | ((uint_t)f2bf(a1o) << 16),
                                    (uint_t*)(Out + (size_t)s * ops + nofs));
    }
}

// ---------------- launch ----------------

extern "C" void kernel_launch(void* const* d_in, const int* in_sizes, int n_in,
                              void* d_out, int out_size, void* d_ws, size_t ws_size,
                              hipStream_t stream) {
    const int N = in_sizes[0] / 128;
    const int E = in_sizes[1] / 2;

    const void* x  = d_in[0];
    const int*  ei = (const int*)d_in[1];

    char* ws = (char*)d_ws;
    size_t used = 0;
    auto alloc = [&](size_t bytes) {
        char* p = ws + used;
        used += (bytes + 255) & ~(size_t)255;
        return p;
    };

    int*   flags   = (int*)alloc(64 * 4);
    int*   deg     = (int*)alloc((size_t)N * 4);
    int*   row_ptr = (int*)alloc((size_t)(N + 1) * 4);
    float* dinv    = (float*)alloc((size_t)N * 4);
    int2*  tmp     = (int2*)alloc((size_t)E * 8);
    uint_t* colw   = (uint_t*)alloc((size_t)E * 4);
    int*   bsum    = (int*)alloc(256 * 4);
    ushort_t* Tcat = (ushort_t*)alloc(256 * 128 * 2);
    ushort_t* T2   = (ushort_t*)alloc(128 * 128 * 2);
    ushort_t* T3   = (ushort_t*)alloc(128 * 128 * 2);
    ushort_t* Tlin = (ushort_t*)alloc(128 * 64 * 2);

    ushort_t* Hbuf = (ushort_t*)alloc((size_t)(N + 1) * 128 * 2);  // 4 planes x (N+1) x 32
    ushort_t* Act1 = (ushort_t*)alloc((size_t)N * 128 * 2);        // 4 planes x N x 32
    ushort_t* Act2 = (ushort_t*)alloc((size_t)N * 128 * 2);
    ushort_t* Xres = (ushort_t*)alloc((size_t)N * 128 * 2);

    if (used > ws_size) return;

    const int PH = (N + 1) * 32;   // H plane stride (elems), has sentinel row N
    const int PA = N * 32;         // Act/Xres plane stride (elems)

    DetectArgs da;
    for (int i = 0; i < 11; ++i) { da.t[i] = d_in[i == 0 ? 0 : i + 1]; da.elems[i] = in_sizes[i == 0 ? 0 : i + 1]; }
    da.ei = ei;
    da.flags = flags;

    const int B = 256;
    int gE4   = ((E + 3) / 4 + B - 1) / B;
    int gPack = (4 * 128 * 128 + 128 * 64) / B;   // 288 blocks = 73728 threads >= N
    int gGemm = (N + 63) / 64;
    int gAgg  = ((N + 15) / 16) * 4;              // (16-node groups) x (4 slices)
    int nb    = (N + 1023) / 1024;                // 49 <= 64 (rowptr self-scan limit)

    k_pack<<<gPack, B, 0, stream>>>(da, Tcat, T2, T3, Tlin, deg, N, Hbuf, PH);
    k_deg<<<gE4, B, 0, stream>>>(ei, E, N, flags, deg, tmp);
    k_bsum<<<nb, B, 0, stream>>>(deg, N, bsum);
    k_rowptr<<<nb, B, 0, stream>>>(deg, bsum, N, row_ptr, dinv);
    k_scatter<<<gE4, B, 0, stream>>>(ei, E, N, flags, row_ptr, tmp, colw);

    // layer 1 (two-phase dual GEMM): H' = (x@W1)*dinv (planar), Xres = x@Wres + bres (planar)
    k_gemm_l1<<<gGemm, B, 0, stream>>>(x, Tcat, d_in[9], Hbuf, PH, Xres, PA, N, flags, dinv);
    k_agg<<<gAgg, B, 0, stream>>>(Hbuf, PH, row_ptr, colw, dinv, d_in[3], 2,
                                  Xres, PA, Act1, N, flags);

    // layer 2
    k_gemm2<8><<<gGemm, B, 0, stream>>>(Act1, PA, T2, nullptr, -1, Hbuf, 1, PH, N, flags, dinv);
    k_agg<<<gAgg, B, 0, stream>>>(Hbuf, PH, row_ptr, colw, dinv, d_in[5], 4,
                                  nullptr, PA, Act2, N, flags);

    // layer 3
    k_gemm2<8><<<gGemm, B, 0, stream>>>(Act2, PA, T3, nullptr, -1, Hbuf, 1, PH, N, flags, dinv);
    k_agg<<<gAgg, B, 0, stream>>>(Hbuf, PH, row_ptr, colw, dinv, d_in[7], 6,
                                  nullptr, PA, Act1, N, flags);

    // final: out = Act1@Wlin + blin (fp32 row-major out, no rowscale)
    k_gemm2<4><<<gGemm, B, 0, stream>>>(Act1, PA, Tlin, d_in[11], 10,
                                        d_out, 0, 0, N, flags, nullptr);
}